// Round 2
// 491.712 us; speedup vs baseline: 1.1906x; 1.1906x over previous
//
#include <hip/hip_runtime.h>

#define RES   32
#define NVOX  (RES * RES * RES)   // 32768
#define NB    8
#define NC    64
#define NPTS  100000
#define NTILE   ((NPTS + 255) / 256)  // 391
#define NTILE64 ((NPTS + 63) / 64)    // 1563

// workspace layout in 4-byte words
#define SUM_OFF  0                          // 24 floats
#define RAD_OFF  32                         // 8 uints
#define CNT_OFF  64                         // NB*NVOX ints        (1 MB)
#define OFF_OFF  (CNT_OFF + NB * NVOX)      // NB*NVOX ints        (1 MB)
#define IR_OFF   (OFF_OFF + NB * NVOX)      // NB*NPTS uints       (3.2 MB)  (idx<<16)|rank
#define FS_OFF   (IR_OFF  + NB * NPTS)      // featS bf16: NB*NPTS*CH*2 bytes

__device__ __forceinline__ unsigned short f2bf(float x) {
    unsigned u = __float_as_uint(x);
    return (unsigned short)((u + 0x7FFFu + ((u >> 16) & 1u)) >> 16);  // RNE
}
__device__ __forceinline__ float bf2f(unsigned short h) {
    return __uint_as_float((unsigned)h << 16);
}

// ---------------------------------------------------------------------------
// Kernel 1: per-batch sum of coords -> ws_sum[b*3+k]
// ---------------------------------------------------------------------------
__global__ void sum_kernel(const float* __restrict__ coords,
                           float* __restrict__ ws_sum) {
    const int b = blockIdx.y;
    const float* cb = coords + (size_t)b * 3 * NPTS;
    float s0 = 0.f, s1 = 0.f, s2 = 0.f;
    for (int n = blockIdx.x * blockDim.x + threadIdx.x; n < NPTS;
         n += blockDim.x * gridDim.x) {
        s0 += cb[n];
        s1 += cb[NPTS + n];
        s2 += cb[2 * NPTS + n];
    }
    for (int off = 32; off > 0; off >>= 1) {
        s0 += __shfl_down(s0, off, 64);
        s1 += __shfl_down(s1, off, 64);
        s2 += __shfl_down(s2, off, 64);
    }
    if ((threadIdx.x & 63) == 0) {
        atomicAdd(&ws_sum[b * 3 + 0], s0);
        atomicAdd(&ws_sum[b * 3 + 1], s1);
        atomicAdd(&ws_sum[b * 3 + 2], s2);
    }
}

// ---------------------------------------------------------------------------
// Kernel 2: per-batch max squared radius -> ws_rad[b] (uint bits, monotone)
// ---------------------------------------------------------------------------
__global__ void rad_kernel(const float* __restrict__ coords,
                           const float* __restrict__ ws_sum,
                           unsigned int* __restrict__ ws_rad) {
#pragma clang fp contract(off)
    const int b = blockIdx.y;
    const float* cb = coords + (size_t)b * 3 * NPTS;
    const float m0 = ws_sum[b * 3 + 0] / (float)NPTS;
    const float m1 = ws_sum[b * 3 + 1] / (float)NPTS;
    const float m2 = ws_sum[b * 3 + 2] / (float)NPTS;
    float mx = 0.f;
    for (int n = blockIdx.x * blockDim.x + threadIdx.x; n < NPTS;
         n += blockDim.x * gridDim.x) {
        float dx = cb[n] - m0;
        float dy = cb[NPTS + n] - m1;
        float dz = cb[2 * NPTS + n] - m2;
        float sq = dx * dx + dy * dy + dz * dz;
        mx = fmaxf(mx, sq);
    }
    for (int off = 32; off > 0; off >>= 1)
        mx = fmaxf(mx, __shfl_down(mx, off, 64));
    if ((threadIdx.x & 63) == 0)
        atomicMax(&ws_rad[b], __float_as_uint(mx));
}

// ---------------------------------------------------------------------------
// Kernel 3: per point: norm coords (output 1), voxel idx, histogram + rank.
// ---------------------------------------------------------------------------
__global__ void index_kernel(const float* __restrict__ coords,
                             const float* __restrict__ ws_sum,
                             const unsigned int* __restrict__ ws_rad,
                             float* __restrict__ norm_out,
                             unsigned int* __restrict__ idxrank,
                             int* __restrict__ counts) {
#pragma clang fp contract(off)
    const int n = blockIdx.x * blockDim.x + threadIdx.x;
    const int b = blockIdx.y;
    if (n >= NPTS) return;

    const float m0 = ws_sum[b * 3 + 0] / (float)NPTS;
    const float m1 = ws_sum[b * 3 + 1] / (float)NPTS;
    const float m2 = ws_sum[b * 3 + 2] / (float)NPTS;
    const float r  = sqrtf(__uint_as_float(ws_rad[b]));
    const float d  = r * 2.0f;   // EPS == 0

    const float* cb = coords + (size_t)b * 3 * NPTS;
    const float x = cb[n] - m0;
    const float y = cb[NPTS + n] - m1;
    const float z = cb[2 * NPTS + n] - m2;

    const float nx = fminf(fmaxf((x / d + 0.5f) * (float)RES, 0.0f), (float)(RES - 1));
    const float ny = fminf(fmaxf((y / d + 0.5f) * (float)RES, 0.0f), (float)(RES - 1));
    const float nz = fminf(fmaxf((z / d + 0.5f) * (float)RES, 0.0f), (float)(RES - 1));

    float* nb_ = norm_out + (size_t)b * 3 * NPTS;
    nb_[n]            = nx;
    nb_[NPTS + n]     = ny;
    nb_[2 * NPTS + n] = nz;

    const int ix = (int)rintf(nx);
    const int iy = (int)rintf(ny);
    const int iz = (int)rintf(nz);
    const int idx = (ix * RES + iy) * RES + iz;

    const int rank = atomicAdd(&counts[b * NVOX + idx], 1);
    idxrank[(size_t)b * NPTS + n] = ((unsigned)idx << 16) | (unsigned)(rank & 0xFFFF);
}

// ---------------------------------------------------------------------------
// Kernel 4: per-batch exclusive scan of 32768 counts -> offsets
// ---------------------------------------------------------------------------
__global__ __launch_bounds__(1024) void scan_kernel(const int* __restrict__ counts,
                                                    int* __restrict__ offsets) {
    const int b = blockIdx.x;
    const int t = threadIdx.x;            // each owns 32 values
    const int base = b * NVOX + t * 32;
    int sum = 0;
#pragma unroll
    for (int i = 0; i < 32; ++i) sum += counts[base + i];

    const int lane = t & 63, wid = t >> 6;  // 16 waves
    int x = sum;
    for (int off = 1; off < 64; off <<= 1) {
        int y = __shfl_up(x, off, 64);
        if (lane >= off) x += y;
    }
    __shared__ int wsum[16];
    if (lane == 63) wsum[wid] = x;
    __syncthreads();
    if (t == 0) {
        int run = 0;
        for (int w = 0; w < 16; ++w) { int tmp = wsum[w]; wsum[w] = run; run += tmp; }
    }
    __syncthreads();
    int pre = x - sum + wsum[wid];
#pragma unroll
    for (int i = 0; i < 32; ++i) {
        offsets[base + i] = pre;
        pre += counts[base + i];
    }
}

// ---------------------------------------------------------------------------
// Kernel 5 (single-pass): permute ALL 64 channels into sorted order (bf16).
//   Block: 64 points x 64 channels via fp32 LDS tile; reads coalesced along
//   n; writes each point's 128B row with 16 consecutive lanes (ushort4).
// ---------------------------------------------------------------------------
__global__ __launch_bounds__(256) void permute64_kernel(
        const float* __restrict__ feat,
        const unsigned int* __restrict__ idxrank,
        const int* __restrict__ offsets,
        unsigned short* __restrict__ fS) {
    __shared__ float tile[64][65];
    __shared__ int posbuf[64];
    const int b  = blockIdx.y;
    const int n0 = blockIdx.x * 64;
    const int t  = threadIdx.x;
    const int tx = t & 63, ty = t >> 6;   // ty 0..3
    const int n  = n0 + tx;
    const float* fb = feat + (size_t)b * NC * NPTS;
    if (n < NPTS) {
#pragma unroll
        for (int c = ty; c < 64; c += 4)
            tile[c][tx] = fb[(size_t)c * NPTS + n];
        if (ty == 0) {
            const unsigned pk = idxrank[(size_t)b * NPTS + n];
            posbuf[tx] = offsets[b * NVOX + (int)(pk >> 16)] + (int)(pk & 0xFFFFu);
        }
    }
    __syncthreads();
    ushort4* fS4 = (ushort4*)fS + (size_t)b * NPTS * 16;
    const int nmax = min(64, NPTS - n0);
    for (int j = t; j < nmax * 16; j += 256) {
        const int r = j >> 4, q = j & 15;     // point r, chunk q (4 channels)
        const int pos = posbuf[r];
        ushort4 v;
        v.x = f2bf(tile[4 * q][r]);
        v.y = f2bf(tile[4 * q + 1][r]);
        v.z = f2bf(tile[4 * q + 2][r]);
        v.w = f2bf(tile[4 * q + 3][r]);
        fS4[(size_t)pos * 16 + q] = v;
    }
}

// ---------------------------------------------------------------------------
// Kernel 6 (single-pass): gather all 64 channels, NO atomics.
//   Restructured for the Gaussian-skewed count distribution:
//   - wave = 8 point-slots x 8 channel-chunks, 16B uint4 loads (1 KB/wave/iter)
//   - dual-accumulator manual unroll -> >=2 loads in flight (ILP)
//   - z-interleaved voxel->wave map (vsel = k*8+wid) spreads the dense
//     central z-band of each column across all 8 waves of the block
//   - empty voxels (~82%) take a wave-uniform early-out, no butterfly
//   - transposed LDS tile [C][65]: conflict-free writes & reads
// ---------------------------------------------------------------------------
__global__ __launch_bounds__(512) void gather64_kernel(
        const unsigned short* __restrict__ fS,
        const int* __restrict__ offsets, const int* __restrict__ counts,
        float* __restrict__ out) {
    __shared__ float tile[NC][65];   // [channel][voxel-in-block], stride 65: no conflicts
    const int b    = blockIdx.y;
    const int v0   = blockIdx.x * 64;
    const int t    = threadIdx.x;
    const int wid  = t >> 6;          // 0..7
    const int lane = t & 63;
    const int cq   = lane & 7;        // 16B channel chunk (8 channels)
    const int ps   = lane >> 3;       // point slot 0..7

    const int svL  = offsets[b * NVOX + v0 + lane];
    const int cntL = counts[b * NVOX + v0 + lane];
    const uint4* fS4 = (const uint4*)fS + (size_t)b * NPTS * 8 + cq;

#define ACC8(A0,A1,A2,A3,A4,A5,A6,A7,d)                      \
    A0 += __uint_as_float((d).x << 16);                      \
    A1 += __uint_as_float((d).x & 0xffff0000u);              \
    A2 += __uint_as_float((d).y << 16);                      \
    A3 += __uint_as_float((d).y & 0xffff0000u);              \
    A4 += __uint_as_float((d).z << 16);                      \
    A5 += __uint_as_float((d).z & 0xffff0000u);              \
    A6 += __uint_as_float((d).w << 16);                      \
    A7 += __uint_as_float((d).w & 0xffff0000u);

#pragma unroll 1
    for (int k = 0; k < 8; ++k) {
        const int vsel = k * 8 + wid;   // z-interleave: balance dense z-bands
        const int s    = __shfl(svL, vsel, 64);
        const int cnt  = __shfl(cntL, vsel, 64);

        if (cnt == 0) {                 // wave-uniform: ~82% of voxels
            if (ps == 0) {
                tile[8 * cq + 0][vsel] = 0.f; tile[8 * cq + 1][vsel] = 0.f;
                tile[8 * cq + 2][vsel] = 0.f; tile[8 * cq + 3][vsel] = 0.f;
            } else if (ps == 1) {
                tile[8 * cq + 4][vsel] = 0.f; tile[8 * cq + 5][vsel] = 0.f;
                tile[8 * cq + 6][vsel] = 0.f; tile[8 * cq + 7][vsel] = 0.f;
            }
            continue;
        }

        float a0 = 0.f, a1 = 0.f, a2 = 0.f, a3 = 0.f,
              a4 = 0.f, a5 = 0.f, a6 = 0.f, a7 = 0.f;
        float c0 = 0.f, c1 = 0.f, c2 = 0.f, c3 = 0.f,
              c4 = 0.f, c5 = 0.f, c6 = 0.f, c7 = 0.f;
        const int e = s + cnt;
        int p = s + ps;
        // dual-accumulator: two independent 16B loads in flight per stage
        for (; p + 8 < e; p += 16) {
            const uint4 d0 = fS4[(size_t)p * 8];
            const uint4 d1 = fS4[(size_t)(p + 8) * 8];
            ACC8(a0, a1, a2, a3, a4, a5, a6, a7, d0)
            ACC8(c0, c1, c2, c3, c4, c5, c6, c7, d1)
        }
        if (p < e) {
            const uint4 d0 = fS4[(size_t)p * 8];
            ACC8(a0, a1, a2, a3, a4, a5, a6, a7, d0)
        }
        a0 += c0; a1 += c1; a2 += c2; a3 += c3;
        a4 += c4; a5 += c5; a6 += c6; a7 += c7;

        // reduce across the 8 point slots (ps bits = lane bits 3..5)
#pragma unroll
        for (int m = 8; m < 64; m <<= 1) {
            a0 += __shfl_xor(a0, m, 64);
            a1 += __shfl_xor(a1, m, 64);
            a2 += __shfl_xor(a2, m, 64);
            a3 += __shfl_xor(a3, m, 64);
            a4 += __shfl_xor(a4, m, 64);
            a5 += __shfl_xor(a5, m, 64);
            a6 += __shfl_xor(a6, m, 64);
            a7 += __shfl_xor(a7, m, 64);
        }

        const float inv = 1.0f / fmaxf((float)cnt, 1.f);
        if (ps == 0) {
            tile[8 * cq + 0][vsel] = a0 * inv; tile[8 * cq + 1][vsel] = a1 * inv;
            tile[8 * cq + 2][vsel] = a2 * inv; tile[8 * cq + 3][vsel] = a3 * inv;
        } else if (ps == 1) {
            tile[8 * cq + 4][vsel] = a4 * inv; tile[8 * cq + 5][vsel] = a5 * inv;
            tile[8 * cq + 6][vsel] = a6 * inv; tile[8 * cq + 7][vsel] = a7 * inv;
        }
    }
#undef ACC8
    __syncthreads();

#pragma unroll
    for (int i = t; i < 64 * NC; i += 512) {
        const int v = i & 63, c = i >> 6;
        out[(size_t)b * NC * NVOX + (size_t)c * NVOX + v0 + v] = tile[c][v];
    }
}

// ---------------------------------------------------------------------------
// Multi-pass kernels (smaller-workspace fallback, CH in {16,8,4,2})
// ---------------------------------------------------------------------------
template <int CH>
__global__ __launch_bounds__(256) void permute_kernel(
        const float* __restrict__ feat,
        const unsigned int* __restrict__ idxrank,
        const int* __restrict__ offsets,
        unsigned short* __restrict__ fS, int c0) {
    __shared__ float tile[CH][257];
    __shared__ int posbuf[256];
    const int b  = blockIdx.y;
    const int n0 = blockIdx.x * 256;
    const int t  = threadIdx.x;
    const int n  = n0 + t;
    const float* fb = feat + (size_t)b * NC * NPTS + (size_t)c0 * NPTS;
    if (n < NPTS) {
        const unsigned pk = idxrank[(size_t)b * NPTS + n];
        posbuf[t] = offsets[b * NVOX + (int)(pk >> 16)] + (int)(pk & 0xFFFFu);
#pragma unroll
        for (int c = 0; c < CH; ++c)
            tile[c][t] = fb[(size_t)c * NPTS + n];
    }
    __syncthreads();
    ushort2* fS2 = (ushort2*)fS + (size_t)b * NPTS * (CH / 2);
    const int nmax = min(256, NPTS - n0);
    for (int j = t; j < nmax * (CH / 2); j += 256) {
        const int r  = j / (CH / 2);
        const int cp = j - r * (CH / 2);
        const int pos = posbuf[r];
        ushort2 v;
        v.x = f2bf(tile[2 * cp][r]);
        v.y = f2bf(tile[2 * cp + 1][r]);
        fS2[(size_t)pos * (CH / 2) + cp] = v;
    }
}

template <int CH>
__global__ __launch_bounds__(512) void gather_kernel(
        const unsigned short* __restrict__ fS,
        const int* __restrict__ offsets, const int* __restrict__ counts,
        float* __restrict__ out, int c0) {
    constexpr int HP  = CH / 2;
    constexpr int PPW = 64 / HP;
    __shared__ float tile[64][CH + 2];
    const int b    = blockIdx.y;
    const int v0   = blockIdx.x * 64;
    const int t    = threadIdx.x;
    const int wid  = t >> 6;
    const int lane = t & 63;
    const int pr   = lane % HP;
    const int ps   = lane / HP;

    const int svL  = offsets[b * NVOX + v0 + lane];
    const int cntL = counts[b * NVOX + v0 + lane];
    const ushort2* fS2 = (const ushort2*)fS + (size_t)b * NPTS * HP;

#pragma unroll
    for (int k = 0; k < 8; ++k) {
        const int vsel = wid * 8 + k;
        const int s    = __shfl(svL, vsel, 64);
        const int cnt  = __shfl(cntL, vsel, 64);
        float ax = 0.f, ay = 0.f;
        const int e = s + cnt;
        for (int p = s + ps; p < e; p += PPW) {
            const ushort2 d = fS2[(size_t)p * HP + pr];
            ax += bf2f(d.x);
            ay += bf2f(d.y);
        }
        for (int m = HP; m < 64; m <<= 1) {
            ax += __shfl_xor(ax, m, 64);
            ay += __shfl_xor(ay, m, 64);
        }
        if (ps == 0) {
            const float cf = fmaxf((float)cnt, 1.f);
            *(float2*)&tile[vsel][2 * pr] = make_float2(ax / cf, ay / cf);
        }
    }
    __syncthreads();

#pragma unroll
    for (int i = t; i < 64 * CH; i += 512) {
        const int v = i & 63, c = i >> 6;
        out[(size_t)b * NC * NVOX + (size_t)(c0 + c) * NVOX + v0 + v] = tile[v][c];
    }
}

// ---------------------------------------------------------------------------
// Tiny-workspace fallback: direct global-atomic scatter + divide
// ---------------------------------------------------------------------------
__global__ void scatter_fb(const float* __restrict__ feat,
                           const unsigned int* __restrict__ idxrank,
                           float* __restrict__ out) {
    const int n = blockIdx.x * 256 + threadIdx.x;
    const int b = blockIdx.y;
    if (n >= NPTS) return;
    const int idx = (int)(idxrank[(size_t)b * NPTS + n] >> 16);
    const float* fb = feat + (size_t)b * NC * NPTS + n;
    float* ob = out + (size_t)b * NC * NVOX + idx;
#pragma unroll 4
    for (int c = 0; c < NC; ++c)
        atomicAdd(ob + (size_t)c * NVOX, fb[(size_t)c * NPTS]);
}

__global__ void div_fb(float* __restrict__ out, const int* __restrict__ counts) {
    const int t = blockIdx.x * blockDim.x + threadIdx.x;
    const int b = t >> 15;
    const int v = t & (NVOX - 1);
    const float cnt = fmaxf((float)counts[t], 1.f);
    float* ob = out + (size_t)b * NC * NVOX + v;
#pragma unroll 8
    for (int c = 0; c < NC; ++c)
        ob[(size_t)c * NVOX] /= cnt;
}

// ---------------------------------------------------------------------------
template <int CH>
static void run_passes(const float* feat, unsigned int* idxrank, int* offsets,
                       int* counts, unsigned short* fS, float* out,
                       hipStream_t stream) {
    for (int c0 = 0; c0 < NC; c0 += CH) {
        permute_kernel<CH><<<dim3(NTILE, NB), 256, 0, stream>>>(
            feat, idxrank, offsets, fS, c0);
        gather_kernel<CH><<<dim3(NVOX / 64, NB), 512, 0, stream>>>(
            fS, offsets, counts, out, c0);
    }
}

extern "C" void kernel_launch(void* const* d_in, const int* in_sizes, int n_in,
                              void* d_out, int out_size, void* d_ws, size_t ws_size,
                              hipStream_t stream) {
    const float* feat   = (const float*)d_in[0];  // [8,64,100000]
    const float* coords = (const float*)d_in[1];  // [8,3,100000]

    float* out      = (float*)d_out;                 // [8,64,32,32,32]
    float* norm_out = out + (size_t)NB * NC * NVOX;  // [8,3,100000]

    float*          ws_sum  = (float*)d_ws + SUM_OFF;
    unsigned int*   ws_rad  = (unsigned int*)d_ws + RAD_OFF;
    int*            counts  = (int*)d_ws + CNT_OFF;
    int*            offsets = (int*)d_ws + OFF_OFF;
    unsigned int*   idxrank = (unsigned int*)d_ws + IR_OFF;
    unsigned short* fS      = (unsigned short*)((int*)d_ws + FS_OFF);

    // largest channel chunk that fits the workspace (bf16 featS)
    int CH = 0;
    for (int ch = 64; ch >= 2; ch >>= 1) {
        const size_t need = (size_t)FS_OFF * 4 + (size_t)NB * NPTS * ch * 2;
        if (ws_size >= need) { CH = ch; break; }
    }
    if (CH == 32) CH = 16;   // no 32-wide template; use 16

    hipMemsetAsync(d_ws, 0, ((size_t)CNT_OFF + (size_t)NB * NVOX) * 4, stream);

    sum_kernel<<<dim3(32, NB), 256, 0, stream>>>(coords, ws_sum);
    rad_kernel<<<dim3(32, NB), 256, 0, stream>>>(coords, ws_sum, ws_rad);
    index_kernel<<<dim3(NTILE, NB), 256, 0, stream>>>(
        coords, ws_sum, ws_rad, norm_out, idxrank, counts);

    if (CH == 0) {
        hipMemsetAsync(d_out, 0, (size_t)NB * NC * NVOX * 4, stream);
        scatter_fb<<<dim3(NTILE, NB), 256, 0, stream>>>(feat, idxrank, out);
        div_fb<<<dim3(NB * NVOX / 256), 256, 0, stream>>>(out, counts);
        return;
    }

    scan_kernel<<<dim3(NB), 1024, 0, stream>>>(counts, offsets);

    if (CH == 64) {
        permute64_kernel<<<dim3(NTILE64, NB), 256, 0, stream>>>(
            feat, idxrank, offsets, fS);
        gather64_kernel<<<dim3(NVOX / 64, NB), 512, 0, stream>>>(
            fS, offsets, counts, out);
    } else {
        switch (CH) {
            case 16: run_passes<16>(feat, idxrank, offsets, counts, fS, out, stream); break;
            case 8:  run_passes<8>(feat, idxrank, offsets, counts, fS, out, stream); break;
            case 4:  run_passes<4>(feat, idxrank, offsets, counts, fS, out, stream); break;
            default: run_passes<2>(feat, idxrank, offsets, counts, fS, out, stream); break;
        }
    }
}

// Round 3
// 487.645 us; speedup vs baseline: 1.2005x; 1.0083x over previous
//
#include <hip/hip_runtime.h>

#define RES   32
#define NVOX  (RES * RES * RES)   // 32768
#define NB    8
#define NC    64
#define NPTS  100000
#define NTILE   ((NPTS + 255) / 256)  // 391
#define NTILE64 ((NPTS + 63) / 64)    // 1563

// workspace layout in 4-byte words
#define SUM_OFF  0                          // 24 floats
#define RAD_OFF  32                         // 8 uints
#define CNT_OFF  64                         // NB*NVOX ints        (1 MB)
#define OFF_OFF  (CNT_OFF + NB * NVOX)      // NB*NVOX ints        (1 MB)
#define IR_OFF   (OFF_OFF + NB * NVOX)      // NB*NPTS uints       (3.2 MB)  (idx<<16)|rank
#define FS_OFF   (IR_OFF  + NB * NPTS)      // featS bf16: NB*NPTS*CH*2 bytes

__device__ __forceinline__ unsigned short f2bf(float x) {
    unsigned u = __float_as_uint(x);
    return (unsigned short)((u + 0x7FFFu + ((u >> 16) & 1u)) >> 16);  // RNE
}
__device__ __forceinline__ float bf2f(unsigned short h) {
    return __uint_as_float((unsigned)h << 16);
}

// ---------------------------------------------------------------------------
// Kernel 1: per-batch sum of coords -> ws_sum[b*3+k]
// ---------------------------------------------------------------------------
__global__ void sum_kernel(const float* __restrict__ coords,
                           float* __restrict__ ws_sum) {
    const int b = blockIdx.y;
    const float* cb = coords + (size_t)b * 3 * NPTS;
    float s0 = 0.f, s1 = 0.f, s2 = 0.f;
    for (int n = blockIdx.x * blockDim.x + threadIdx.x; n < NPTS;
         n += blockDim.x * gridDim.x) {
        s0 += cb[n];
        s1 += cb[NPTS + n];
        s2 += cb[2 * NPTS + n];
    }
    for (int off = 32; off > 0; off >>= 1) {
        s0 += __shfl_down(s0, off, 64);
        s1 += __shfl_down(s1, off, 64);
        s2 += __shfl_down(s2, off, 64);
    }
    if ((threadIdx.x & 63) == 0) {
        atomicAdd(&ws_sum[b * 3 + 0], s0);
        atomicAdd(&ws_sum[b * 3 + 1], s1);
        atomicAdd(&ws_sum[b * 3 + 2], s2);
    }
}

// ---------------------------------------------------------------------------
// Kernel 2: per-batch max squared radius -> ws_rad[b] (uint bits, monotone)
// ---------------------------------------------------------------------------
__global__ void rad_kernel(const float* __restrict__ coords,
                           const float* __restrict__ ws_sum,
                           unsigned int* __restrict__ ws_rad) {
#pragma clang fp contract(off)
    const int b = blockIdx.y;
    const float* cb = coords + (size_t)b * 3 * NPTS;
    const float m0 = ws_sum[b * 3 + 0] / (float)NPTS;
    const float m1 = ws_sum[b * 3 + 1] / (float)NPTS;
    const float m2 = ws_sum[b * 3 + 2] / (float)NPTS;
    float mx = 0.f;
    for (int n = blockIdx.x * blockDim.x + threadIdx.x; n < NPTS;
         n += blockDim.x * gridDim.x) {
        float dx = cb[n] - m0;
        float dy = cb[NPTS + n] - m1;
        float dz = cb[2 * NPTS + n] - m2;
        float sq = dx * dx + dy * dy + dz * dz;
        mx = fmaxf(mx, sq);
    }
    for (int off = 32; off > 0; off >>= 1)
        mx = fmaxf(mx, __shfl_down(mx, off, 64));
    if ((threadIdx.x & 63) == 0)
        atomicMax(&ws_rad[b], __float_as_uint(mx));
}

// ---------------------------------------------------------------------------
// Kernel 3: per point: norm coords (output 1), voxel idx, histogram + rank.
// ---------------------------------------------------------------------------
__global__ void index_kernel(const float* __restrict__ coords,
                             const float* __restrict__ ws_sum,
                             const unsigned int* __restrict__ ws_rad,
                             float* __restrict__ norm_out,
                             unsigned int* __restrict__ idxrank,
                             int* __restrict__ counts) {
#pragma clang fp contract(off)
    const int n = blockIdx.x * blockDim.x + threadIdx.x;
    const int b = blockIdx.y;
    if (n >= NPTS) return;

    const float m0 = ws_sum[b * 3 + 0] / (float)NPTS;
    const float m1 = ws_sum[b * 3 + 1] / (float)NPTS;
    const float m2 = ws_sum[b * 3 + 2] / (float)NPTS;
    const float r  = sqrtf(__uint_as_float(ws_rad[b]));
    const float d  = r * 2.0f;   // EPS == 0

    const float* cb = coords + (size_t)b * 3 * NPTS;
    const float x = cb[n] - m0;
    const float y = cb[NPTS + n] - m1;
    const float z = cb[2 * NPTS + n] - m2;

    const float nx = fminf(fmaxf((x / d + 0.5f) * (float)RES, 0.0f), (float)(RES - 1));
    const float ny = fminf(fmaxf((y / d + 0.5f) * (float)RES, 0.0f), (float)(RES - 1));
    const float nz = fminf(fmaxf((z / d + 0.5f) * (float)RES, 0.0f), (float)(RES - 1));

    float* nb_ = norm_out + (size_t)b * 3 * NPTS;
    nb_[n]            = nx;
    nb_[NPTS + n]     = ny;
    nb_[2 * NPTS + n] = nz;

    const int ix = (int)rintf(nx);
    const int iy = (int)rintf(ny);
    const int iz = (int)rintf(nz);
    const int idx = (ix * RES + iy) * RES + iz;

    const int rank = atomicAdd(&counts[b * NVOX + idx], 1);
    idxrank[(size_t)b * NPTS + n] = ((unsigned)idx << 16) | (unsigned)(rank & 0xFFFF);
}

// ---------------------------------------------------------------------------
// Kernel 4: per-batch exclusive scan of 32768 counts -> offsets
// ---------------------------------------------------------------------------
__global__ __launch_bounds__(1024) void scan_kernel(const int* __restrict__ counts,
                                                    int* __restrict__ offsets) {
    const int b = blockIdx.x;
    const int t = threadIdx.x;            // each owns 32 values
    const int base = b * NVOX + t * 32;
    int sum = 0;
#pragma unroll
    for (int i = 0; i < 32; ++i) sum += counts[base + i];

    const int lane = t & 63, wid = t >> 6;  // 16 waves
    int x = sum;
    for (int off = 1; off < 64; off <<= 1) {
        int y = __shfl_up(x, off, 64);
        if (lane >= off) x += y;
    }
    __shared__ int wsum[16];
    if (lane == 63) wsum[wid] = x;
    __syncthreads();
    if (t == 0) {
        int run = 0;
        for (int w = 0; w < 16; ++w) { int tmp = wsum[w]; wsum[w] = run; run += tmp; }
    }
    __syncthreads();
    int pre = x - sum + wsum[wid];
#pragma unroll
    for (int i = 0; i < 32; ++i) {
        offsets[base + i] = pre;
        pre += counts[base + i];
    }
}

// ---------------------------------------------------------------------------
// Kernel 5 (single-pass): permute ALL 64 channels into sorted order (bf16).
//   256-point blocks: float4 global loads (16B/lane), bf16 LDS tile (33 KB,
//   4 blocks/CU), phase 2 is pack-only. Writes each point's 128B row with
//   16 consecutive lanes (ushort4).
// ---------------------------------------------------------------------------
__global__ __launch_bounds__(256) void permute64_kernel(
        const float* __restrict__ feat,
        const unsigned int* __restrict__ idxrank,
        const int* __restrict__ offsets,
        unsigned short* __restrict__ fS) {
    __shared__ unsigned short tile[64][260];   // bf16; stride 260 -> 8B-aligned rows
    __shared__ int posbuf[256];
    const int b  = blockIdx.y;
    const int n0 = blockIdx.x * 256;
    const int t  = threadIdx.x;
    const int tx = t & 63, ty = t >> 6;   // ty 0..3
    const float* fb = feat + (size_t)b * NC * NPTS;

    {   // position of each point (sorted destination)
        const int n = n0 + t;
        if (n < NPTS) {
            const unsigned pk = idxrank[(size_t)b * NPTS + n];
            posbuf[t] = offsets[b * NVOX + (int)(pk >> 16)] + (int)(pk & 0xFFFFu);
        }
    }

    // load 256 points x 64 ch as float4 (NPTS % 4 == 0), convert to bf16
    const int n4 = n0 + 4 * tx;
    if (n4 < NPTS) {
#pragma unroll
        for (int c = ty; c < 64; c += 4) {
            const float4 v = *(const float4*)&fb[(size_t)c * NPTS + n4];
            unsigned short* row = &tile[c][4 * tx];
            row[0] = f2bf(v.x); row[1] = f2bf(v.y);
            row[2] = f2bf(v.z); row[3] = f2bf(v.w);
        }
    }
    __syncthreads();

    ushort4* fS4 = (ushort4*)fS + (size_t)b * NPTS * 16;
    const int nmax = min(256, NPTS - n0);
    for (int j = t; j < nmax * 16; j += 256) {
        const int r = j >> 4, q = j & 15;     // point r, chunk q (4 channels)
        const int pos = posbuf[r];
        ushort4 v;
        v.x = tile[4 * q][r];
        v.y = tile[4 * q + 1][r];
        v.z = tile[4 * q + 2][r];
        v.w = tile[4 * q + 3][r];
        fS4[(size_t)pos * 16 + q] = v;
    }
}

// ---------------------------------------------------------------------------
// Kernel 6 (single-pass): gather all 64 channels, NO atomics.
//   - wave = 8 point-slots x 8 channel-chunks, 16B uint4 loads
//   - QUAD-issue loads (4 in flight, imm-offset folded) + dual/single tail
//   - z-interleaved voxel->wave map (vsel = k*8+wid)
//   - empty voxels: 64-lane zero-fill early-out
//   - transposed LDS tile [C][65]: conflict-free writes & reads
// ---------------------------------------------------------------------------
__global__ __launch_bounds__(512) void gather64_kernel(
        const unsigned short* __restrict__ fS,
        const int* __restrict__ offsets, const int* __restrict__ counts,
        float* __restrict__ out) {
    __shared__ float tile[NC][65];   // [channel][voxel-in-block]
    const int b    = blockIdx.y;
    const int v0   = blockIdx.x * 64;
    const int t    = threadIdx.x;
    const int wid  = t >> 6;          // 0..7
    const int lane = t & 63;
    const int cq   = lane & 7;        // 16B channel chunk (8 channels)
    const int ps   = lane >> 3;       // point slot 0..7

    const int svL  = offsets[b * NVOX + v0 + lane];
    const int cntL = counts[b * NVOX + v0 + lane];
    const uint4* fS4 = (const uint4*)fS + (size_t)b * NPTS * 8 + cq;

#define ACC8(A0,A1,A2,A3,A4,A5,A6,A7,d)                      \
    A0 += __uint_as_float((d).x << 16);                      \
    A1 += __uint_as_float((d).x & 0xffff0000u);              \
    A2 += __uint_as_float((d).y << 16);                      \
    A3 += __uint_as_float((d).y & 0xffff0000u);              \
    A4 += __uint_as_float((d).z << 16);                      \
    A5 += __uint_as_float((d).z & 0xffff0000u);              \
    A6 += __uint_as_float((d).w << 16);                      \
    A7 += __uint_as_float((d).w & 0xffff0000u);

#pragma unroll 1
    for (int k = 0; k < 8; ++k) {
        const int vsel = k * 8 + wid;   // z-interleave: balance dense z-bands
        const int s    = __shfl(svL, vsel, 64);
        const int cnt  = __shfl(cntL, vsel, 64);

        if (cnt == 0) {                 // wave-uniform: ~82% of voxels
            tile[lane][vsel] = 0.f;     // lane = channel, 2-way alias = free
            continue;
        }

        float a0 = 0.f, a1 = 0.f, a2 = 0.f, a3 = 0.f,
              a4 = 0.f, a5 = 0.f, a6 = 0.f, a7 = 0.f;
        float c0 = 0.f, c1 = 0.f, c2 = 0.f, c3 = 0.f,
              c4 = 0.f, c5 = 0.f, c6 = 0.f, c7 = 0.f;
        const int e = s + cnt;
        int p = s + ps;
        // quad-issue: 4 independent 16B loads in flight per stage
        for (; p + 24 < e; p += 32) {
            const uint4 d0 = fS4[(size_t)(p     ) * 8];
            const uint4 d1 = fS4[(size_t)(p +  8) * 8];
            const uint4 d2 = fS4[(size_t)(p + 16) * 8];
            const uint4 d3 = fS4[(size_t)(p + 24) * 8];
            ACC8(a0, a1, a2, a3, a4, a5, a6, a7, d0)
            ACC8(c0, c1, c2, c3, c4, c5, c6, c7, d1)
            ACC8(a0, a1, a2, a3, a4, a5, a6, a7, d2)
            ACC8(c0, c1, c2, c3, c4, c5, c6, c7, d3)
        }
        if (p + 8 < e) {                // 2-3 loads remain: dual
            const uint4 d0 = fS4[(size_t)p * 8];
            const uint4 d1 = fS4[(size_t)(p + 8) * 8];
            ACC8(a0, a1, a2, a3, a4, a5, a6, a7, d0)
            ACC8(c0, c1, c2, c3, c4, c5, c6, c7, d1)
            p += 16;
        }
        if (p < e) {                    // last load
            const uint4 d0 = fS4[(size_t)p * 8];
            ACC8(a0, a1, a2, a3, a4, a5, a6, a7, d0)
        }
        a0 += c0; a1 += c1; a2 += c2; a3 += c3;
        a4 += c4; a5 += c5; a6 += c6; a7 += c7;

        // reduce across the 8 point slots (ps bits = lane bits 3..5)
#pragma unroll
        for (int m = 8; m < 64; m <<= 1) {
            a0 += __shfl_xor(a0, m, 64);
            a1 += __shfl_xor(a1, m, 64);
            a2 += __shfl_xor(a2, m, 64);
            a3 += __shfl_xor(a3, m, 64);
            a4 += __shfl_xor(a4, m, 64);
            a5 += __shfl_xor(a5, m, 64);
            a6 += __shfl_xor(a6, m, 64);
            a7 += __shfl_xor(a7, m, 64);
        }

        const float inv = 1.0f / fmaxf((float)cnt, 1.f);
        if (ps == 0) {
            tile[8 * cq + 0][vsel] = a0 * inv; tile[8 * cq + 1][vsel] = a1 * inv;
            tile[8 * cq + 2][vsel] = a2 * inv; tile[8 * cq + 3][vsel] = a3 * inv;
        } else if (ps == 1) {
            tile[8 * cq + 4][vsel] = a4 * inv; tile[8 * cq + 5][vsel] = a5 * inv;
            tile[8 * cq + 6][vsel] = a6 * inv; tile[8 * cq + 7][vsel] = a7 * inv;
        }
    }
#undef ACC8
    __syncthreads();

#pragma unroll
    for (int i = t; i < 64 * NC; i += 512) {
        const int v = i & 63, c = i >> 6;
        out[(size_t)b * NC * NVOX + (size_t)c * NVOX + v0 + v] = tile[c][v];
    }
}

// ---------------------------------------------------------------------------
// Multi-pass kernels (smaller-workspace fallback, CH in {16,8,4,2})
// ---------------------------------------------------------------------------
template <int CH>
__global__ __launch_bounds__(256) void permute_kernel(
        const float* __restrict__ feat,
        const unsigned int* __restrict__ idxrank,
        const int* __restrict__ offsets,
        unsigned short* __restrict__ fS, int c0) {
    __shared__ float tile[CH][257];
    __shared__ int posbuf[256];
    const int b  = blockIdx.y;
    const int n0 = blockIdx.x * 256;
    const int t  = threadIdx.x;
    const int n  = n0 + t;
    const float* fb = feat + (size_t)b * NC * NPTS + (size_t)c0 * NPTS;
    if (n < NPTS) {
        const unsigned pk = idxrank[(size_t)b * NPTS + n];
        posbuf[t] = offsets[b * NVOX + (int)(pk >> 16)] + (int)(pk & 0xFFFFu);
#pragma unroll
        for (int c = 0; c < CH; ++c)
            tile[c][t] = fb[(size_t)c * NPTS + n];
    }
    __syncthreads();
    ushort2* fS2 = (ushort2*)fS + (size_t)b * NPTS * (CH / 2);
    const int nmax = min(256, NPTS - n0);
    for (int j = t; j < nmax * (CH / 2); j += 256) {
        const int r  = j / (CH / 2);
        const int cp = j - r * (CH / 2);
        const int pos = posbuf[r];
        ushort2 v;
        v.x = f2bf(tile[2 * cp][r]);
        v.y = f2bf(tile[2 * cp + 1][r]);
        fS2[(size_t)pos * (CH / 2) + cp] = v;
    }
}

template <int CH>
__global__ __launch_bounds__(512) void gather_kernel(
        const unsigned short* __restrict__ fS,
        const int* __restrict__ offsets, const int* __restrict__ counts,
        float* __restrict__ out, int c0) {
    constexpr int HP  = CH / 2;
    constexpr int PPW = 64 / HP;
    __shared__ float tile[64][CH + 2];
    const int b    = blockIdx.y;
    const int v0   = blockIdx.x * 64;
    const int t    = threadIdx.x;
    const int wid  = t >> 6;
    const int lane = t & 63;
    const int pr   = lane % HP;
    const int ps   = lane / HP;

    const int svL  = offsets[b * NVOX + v0 + lane];
    const int cntL = counts[b * NVOX + v0 + lane];
    const ushort2* fS2 = (const ushort2*)fS + (size_t)b * NPTS * HP;

#pragma unroll
    for (int k = 0; k < 8; ++k) {
        const int vsel = wid * 8 + k;
        const int s    = __shfl(svL, vsel, 64);
        const int cnt  = __shfl(cntL, vsel, 64);
        float ax = 0.f, ay = 0.f;
        const int e = s + cnt;
        for (int p = s + ps; p < e; p += PPW) {
            const ushort2 d = fS2[(size_t)p * HP + pr];
            ax += bf2f(d.x);
            ay += bf2f(d.y);
        }
        for (int m = HP; m < 64; m <<= 1) {
            ax += __shfl_xor(ax, m, 64);
            ay += __shfl_xor(ay, m, 64);
        }
        if (ps == 0) {
            const float cf = fmaxf((float)cnt, 1.f);
            *(float2*)&tile[vsel][2 * pr] = make_float2(ax / cf, ay / cf);
        }
    }
    __syncthreads();

#pragma unroll
    for (int i = t; i < 64 * CH; i += 512) {
        const int v = i & 63, c = i >> 6;
        out[(size_t)b * NC * NVOX + (size_t)(c0 + c) * NVOX + v0 + v] = tile[v][c];
    }
}

// ---------------------------------------------------------------------------
// Tiny-workspace fallback: direct global-atomic scatter + divide
// ---------------------------------------------------------------------------
__global__ void scatter_fb(const float* __restrict__ feat,
                           const unsigned int* __restrict__ idxrank,
                           float* __restrict__ out) {
    const int n = blockIdx.x * 256 + threadIdx.x;
    const int b = blockIdx.y;
    if (n >= NPTS) return;
    const int idx = (int)(idxrank[(size_t)b * NPTS + n] >> 16);
    const float* fb = feat + (size_t)b * NC * NPTS + n;
    float* ob = out + (size_t)b * NC * NVOX + idx;
#pragma unroll 4
    for (int c = 0; c < NC; ++c)
        atomicAdd(ob + (size_t)c * NVOX, fb[(size_t)c * NPTS]);
}

__global__ void div_fb(float* __restrict__ out, const int* __restrict__ counts) {
    const int t = blockIdx.x * blockDim.x + threadIdx.x;
    const int b = t >> 15;
    const int v = t & (NVOX - 1);
    const float cnt = fmaxf((float)counts[t], 1.f);
    float* ob = out + (size_t)b * NC * NVOX + v;
#pragma unroll 8
    for (int c = 0; c < NC; ++c)
        ob[(size_t)c * NVOX] /= cnt;
}

// ---------------------------------------------------------------------------
template <int CH>
static void run_passes(const float* feat, unsigned int* idxrank, int* offsets,
                       int* counts, unsigned short* fS, float* out,
                       hipStream_t stream) {
    for (int c0 = 0; c0 < NC; c0 += CH) {
        permute_kernel<CH><<<dim3(NTILE, NB), 256, 0, stream>>>(
            feat, idxrank, offsets, fS, c0);
        gather_kernel<CH><<<dim3(NVOX / 64, NB), 512, 0, stream>>>(
            fS, offsets, counts, out, c0);
    }
}

extern "C" void kernel_launch(void* const* d_in, const int* in_sizes, int n_in,
                              void* d_out, int out_size, void* d_ws, size_t ws_size,
                              hipStream_t stream) {
    const float* feat   = (const float*)d_in[0];  // [8,64,100000]
    const float* coords = (const float*)d_in[1];  // [8,3,100000]

    float* out      = (float*)d_out;                 // [8,64,32,32,32]
    float* norm_out = out + (size_t)NB * NC * NVOX;  // [8,3,100000]

    float*          ws_sum  = (float*)d_ws + SUM_OFF;
    unsigned int*   ws_rad  = (unsigned int*)d_ws + RAD_OFF;
    int*            counts  = (int*)d_ws + CNT_OFF;
    int*            offsets = (int*)d_ws + OFF_OFF;
    unsigned int*   idxrank = (unsigned int*)d_ws + IR_OFF;
    unsigned short* fS      = (unsigned short*)((int*)d_ws + FS_OFF);

    // largest channel chunk that fits the workspace (bf16 featS)
    int CH = 0;
    for (int ch = 64; ch >= 2; ch >>= 1) {
        const size_t need = (size_t)FS_OFF * 4 + (size_t)NB * NPTS * ch * 2;
        if (ws_size >= need) { CH = ch; break; }
    }
    if (CH == 32) CH = 16;   // no 32-wide template; use 16

    hipMemsetAsync(d_ws, 0, ((size_t)CNT_OFF + (size_t)NB * NVOX) * 4, stream);

    sum_kernel<<<dim3(32, NB), 256, 0, stream>>>(coords, ws_sum);
    rad_kernel<<<dim3(32, NB), 256, 0, stream>>>(coords, ws_sum, ws_rad);
    index_kernel<<<dim3(NTILE, NB), 256, 0, stream>>>(
        coords, ws_sum, ws_rad, norm_out, idxrank, counts);

    if (CH == 0) {
        hipMemsetAsync(d_out, 0, (size_t)NB * NC * NVOX * 4, stream);
        scatter_fb<<<dim3(NTILE, NB), 256, 0, stream>>>(feat, idxrank, out);
        div_fb<<<dim3(NB * NVOX / 256), 256, 0, stream>>>(out, counts);
        return;
    }

    scan_kernel<<<dim3(NB), 1024, 0, stream>>>(counts, offsets);

    if (CH == 64) {
        permute64_kernel<<<dim3(NTILE, NB), 256, 0, stream>>>(
            feat, idxrank, offsets, fS);
        gather64_kernel<<<dim3(NVOX / 64, NB), 512, 0, stream>>>(
            fS, offsets, counts, out);
    } else {
        switch (CH) {
            case 16: run_passes<16>(feat, idxrank, offsets, counts, fS, out, stream); break;
            case 8:  run_passes<8>(feat, idxrank, offsets, counts, fS, out, stream); break;
            case 4:  run_passes<4>(feat, idxrank, offsets, counts, fS, out, stream); break;
            default: run_passes<2>(feat, idxrank, offsets, counts, fS, out, stream); break;
        }
    }
}

// Round 5
// 477.420 us; speedup vs baseline: 1.2262x; 1.0214x over previous
//
#include <hip/hip_runtime.h>

#define RES   32
#define NVOX  (RES * RES * RES)   // 32768
#define NB    8
#define NC    64
#define NPTS  100000
#define NTILE   ((NPTS + 255) / 256)      // 391
#define NTILE4  ((NPTS / 4 + 255) / 256)  // 98  (4 points per thread)

// workspace layout in 4-byte words
#define SUM_OFF  0                          // 24 floats
#define RAD_OFF  32                         // 8 uints
#define CNT_OFF  64                         // NB*NVOX ints        (1 MB)
#define OFF_OFF  (CNT_OFF + NB * NVOX)      // NB*NVOX ints        (1 MB)
#define IR_OFF   (OFF_OFF + NB * NVOX)      // NB*NPTS uints       (3.2 MB)  (idx<<16)|rank
#define FS_OFF   (IR_OFF  + NB * NPTS)      // featS bf16: NB*NPTS*CH*2 bytes

// native Clang vectors for nontemporal builtins (HIP_vector_type is a struct
// and __builtin_nontemporal_store rejects it)
typedef float          f32x4 __attribute__((ext_vector_type(4)));
typedef unsigned int   u32x4 __attribute__((ext_vector_type(4)));
typedef unsigned short u16x4 __attribute__((ext_vector_type(4)));

__device__ __forceinline__ void nt_store_f4(const float4& v, float* p) {
    f32x4 w = {v.x, v.y, v.z, v.w};
    __builtin_nontemporal_store(w, (f32x4*)p);
}
__device__ __forceinline__ void nt_store_u4(const uint4& v, unsigned int* p) {
    u32x4 w = {v.x, v.y, v.z, v.w};
    __builtin_nontemporal_store(w, (u32x4*)p);
}
__device__ __forceinline__ void nt_store_us4(const ushort4& v, unsigned short* p) {
    u16x4 w = {v.x, v.y, v.z, v.w};
    __builtin_nontemporal_store(w, (u16x4*)p);
}

__device__ __forceinline__ unsigned short f2bf(float x) {
    unsigned u = __float_as_uint(x);
    return (unsigned short)((u + 0x7FFFu + ((u >> 16) & 1u)) >> 16);  // RNE
}
__device__ __forceinline__ float bf2f(unsigned short h) {
    return __uint_as_float((unsigned)h << 16);
}

// ---------------------------------------------------------------------------
// Kernel 1: per-batch sum of coords -> ws_sum[b*3+k]   (float4, 4 pts/iter)
// ---------------------------------------------------------------------------
__global__ void sum_kernel(const float* __restrict__ coords,
                           float* __restrict__ ws_sum) {
    const int b = blockIdx.y;
    const float* cb = coords + (size_t)b * 3 * NPTS;
    float s0 = 0.f, s1 = 0.f, s2 = 0.f;
    for (int i = blockIdx.x * blockDim.x + threadIdx.x; i < NPTS / 4;
         i += blockDim.x * gridDim.x) {
        const float4 a = *(const float4*)&cb[4 * i];
        const float4 c = *(const float4*)&cb[NPTS + 4 * i];
        const float4 d = *(const float4*)&cb[2 * NPTS + 4 * i];
        s0 += (a.x + a.y) + (a.z + a.w);
        s1 += (c.x + c.y) + (c.z + c.w);
        s2 += (d.x + d.y) + (d.z + d.w);
    }
    for (int off = 32; off > 0; off >>= 1) {
        s0 += __shfl_down(s0, off, 64);
        s1 += __shfl_down(s1, off, 64);
        s2 += __shfl_down(s2, off, 64);
    }
    if ((threadIdx.x & 63) == 0) {
        atomicAdd(&ws_sum[b * 3 + 0], s0);
        atomicAdd(&ws_sum[b * 3 + 1], s1);
        atomicAdd(&ws_sum[b * 3 + 2], s2);
    }
}

// ---------------------------------------------------------------------------
// Kernel 2: per-batch max squared radius -> ws_rad[b]  (float4, 4 pts/iter)
// ---------------------------------------------------------------------------
__global__ void rad_kernel(const float* __restrict__ coords,
                           const float* __restrict__ ws_sum,
                           unsigned int* __restrict__ ws_rad) {
#pragma clang fp contract(off)
    const int b = blockIdx.y;
    const float* cb = coords + (size_t)b * 3 * NPTS;
    const float m0 = ws_sum[b * 3 + 0] / (float)NPTS;
    const float m1 = ws_sum[b * 3 + 1] / (float)NPTS;
    const float m2 = ws_sum[b * 3 + 2] / (float)NPTS;
    float mx = 0.f;
    for (int i = blockIdx.x * blockDim.x + threadIdx.x; i < NPTS / 4;
         i += blockDim.x * gridDim.x) {
        const float4 a = *(const float4*)&cb[4 * i];
        const float4 c = *(const float4*)&cb[NPTS + 4 * i];
        const float4 d = *(const float4*)&cb[2 * NPTS + 4 * i];
        const float dx0 = a.x - m0, dy0 = c.x - m1, dz0 = d.x - m2;
        const float dx1 = a.y - m0, dy1 = c.y - m1, dz1 = d.y - m2;
        const float dx2 = a.z - m0, dy2 = c.z - m1, dz2 = d.z - m2;
        const float dx3 = a.w - m0, dy3 = c.w - m1, dz3 = d.w - m2;
        mx = fmaxf(mx, dx0 * dx0 + dy0 * dy0 + dz0 * dz0);
        mx = fmaxf(mx, dx1 * dx1 + dy1 * dy1 + dz1 * dz1);
        mx = fmaxf(mx, dx2 * dx2 + dy2 * dy2 + dz2 * dz2);
        mx = fmaxf(mx, dx3 * dx3 + dy3 * dy3 + dz3 * dz3);
    }
    for (int off = 32; off > 0; off >>= 1)
        mx = fmaxf(mx, __shfl_down(mx, off, 64));
    if ((threadIdx.x & 63) == 0)
        atomicMax(&ws_rad[b], __float_as_uint(mx));
}

// ---------------------------------------------------------------------------
// Kernel 3: per point: norm coords (output 1), voxel idx, histogram + rank.
//   4 points per thread: float4 loads, nt float4/uint4 stores.
// ---------------------------------------------------------------------------
__global__ void index_kernel(const float* __restrict__ coords,
                             const float* __restrict__ ws_sum,
                             const unsigned int* __restrict__ ws_rad,
                             float* __restrict__ norm_out,
                             unsigned int* __restrict__ idxrank,
                             int* __restrict__ counts) {
#pragma clang fp contract(off)
    const int i = blockIdx.x * blockDim.x + threadIdx.x;
    const int b = blockIdx.y;
    const int n4 = i * 4;
    if (n4 >= NPTS) return;   // NPTS % 4 == 0 -> full quads only

    const float m0 = ws_sum[b * 3 + 0] / (float)NPTS;
    const float m1 = ws_sum[b * 3 + 1] / (float)NPTS;
    const float m2 = ws_sum[b * 3 + 2] / (float)NPTS;
    const float r  = sqrtf(__uint_as_float(ws_rad[b]));
    const float d  = r * 2.0f;   // EPS == 0

    const float* cb = coords + (size_t)b * 3 * NPTS;
    const float4 xs = *(const float4*)&cb[n4];
    const float4 ys = *(const float4*)&cb[NPTS + n4];
    const float4 zs = *(const float4*)&cb[2 * NPTS + n4];

    float4 nx4, ny4, nz4;
    int idx0, idx1, idx2, idx3;
#define DOPT(J, OUTX, OUTY, OUTZ, IDX)                                         \
    {                                                                          \
        const float x = xs.J - m0, y = ys.J - m1, z = zs.J - m2;               \
        const float nx = fminf(fmaxf((x / d + 0.5f) * (float)RES, 0.0f),       \
                               (float)(RES - 1));                              \
        const float ny = fminf(fmaxf((y / d + 0.5f) * (float)RES, 0.0f),       \
                               (float)(RES - 1));                              \
        const float nz = fminf(fmaxf((z / d + 0.5f) * (float)RES, 0.0f),       \
                               (float)(RES - 1));                              \
        OUTX = nx; OUTY = ny; OUTZ = nz;                                       \
        IDX = ((int)rintf(nx) * RES + (int)rintf(ny)) * RES + (int)rintf(nz);  \
    }
    DOPT(x, nx4.x, ny4.x, nz4.x, idx0)
    DOPT(y, nx4.y, ny4.y, nz4.y, idx1)
    DOPT(z, nx4.z, ny4.z, nz4.z, idx2)
    DOPT(w, nx4.w, ny4.w, nz4.w, idx3)
#undef DOPT

    float* nb_ = norm_out + (size_t)b * 3 * NPTS;
    nt_store_f4(nx4, &nb_[n4]);
    nt_store_f4(ny4, &nb_[NPTS + n4]);
    nt_store_f4(nz4, &nb_[2 * NPTS + n4]);

    int* cnt_b = counts + (size_t)b * NVOX;
    uint4 ir;
    ir.x = ((unsigned)idx0 << 16) | (unsigned)(atomicAdd(&cnt_b[idx0], 1) & 0xFFFF);
    ir.y = ((unsigned)idx1 << 16) | (unsigned)(atomicAdd(&cnt_b[idx1], 1) & 0xFFFF);
    ir.z = ((unsigned)idx2 << 16) | (unsigned)(atomicAdd(&cnt_b[idx2], 1) & 0xFFFF);
    ir.w = ((unsigned)idx3 << 16) | (unsigned)(atomicAdd(&cnt_b[idx3], 1) & 0xFFFF);
    nt_store_u4(ir, &idxrank[(size_t)b * NPTS + n4]);
}

// ---------------------------------------------------------------------------
// Kernel 4: per-batch exclusive scan of 32768 counts -> offsets (int4 I/O)
// ---------------------------------------------------------------------------
__global__ __launch_bounds__(1024) void scan_kernel(const int* __restrict__ counts,
                                                    int* __restrict__ offsets) {
    const int b = blockIdx.x;
    const int t = threadIdx.x;            // each owns 32 values
    const int base = b * NVOX + t * 32;
    const int4* cp4 = (const int4*)(counts + base);
    int4* op4 = (int4*)(offsets + base);

    const int4 q0 = cp4[0], q1 = cp4[1], q2 = cp4[2], q3 = cp4[3];
    const int4 q4 = cp4[4], q5 = cp4[5], q6 = cp4[6], q7 = cp4[7];
#define QS(Q) ((Q.x + Q.y) + (Q.z + Q.w))
    const int sum = ((QS(q0) + QS(q1)) + (QS(q2) + QS(q3))) +
                    ((QS(q4) + QS(q5)) + (QS(q6) + QS(q7)));
#undef QS

    const int lane = t & 63, wid = t >> 6;  // 16 waves
    int x = sum;
    for (int off = 1; off < 64; off <<= 1) {
        int y = __shfl_up(x, off, 64);
        if (lane >= off) x += y;
    }
    __shared__ int wsum[16];
    if (lane == 63) wsum[wid] = x;
    __syncthreads();
    if (t == 0) {
        int run = 0;
        for (int w = 0; w < 16; ++w) { int tmp = wsum[w]; wsum[w] = run; run += tmp; }
    }
    __syncthreads();
    int run = x - sum + wsum[wid];
#define EMIT(Q, S)                                                   \
    {                                                                \
        int4 o;                                                      \
        o.x = run; run += Q.x; o.y = run; run += Q.y;                \
        o.z = run; run += Q.z; o.w = run; run += Q.w;                \
        op4[S] = o;                                                  \
    }
    EMIT(q0, 0) EMIT(q1, 1) EMIT(q2, 2) EMIT(q3, 3)
    EMIT(q4, 4) EMIT(q5, 5) EMIT(q6, 6) EMIT(q7, 7)
#undef EMIT
}

// ---------------------------------------------------------------------------
// Kernel 5 (single-pass): permute ALL 64 channels into sorted order (bf16).
//   256-point blocks: float4 global loads (16B/lane), bf16 LDS tile, phase 2
//   pack-only; scattered 128B-row writes are NONTEMPORAL (full-line, no L2
//   allocate -> no write-allocate thrash; gather reads them from L3).
// ---------------------------------------------------------------------------
__global__ __launch_bounds__(256) void permute64_kernel(
        const float* __restrict__ feat,
        const unsigned int* __restrict__ idxrank,
        const int* __restrict__ offsets,
        unsigned short* __restrict__ fS) {
    __shared__ unsigned short tile[64][260];   // bf16; stride 260 -> 8B-aligned rows
    __shared__ int posbuf[256];
    const int b  = blockIdx.y;
    const int n0 = blockIdx.x * 256;
    const int t  = threadIdx.x;
    const int tx = t & 63, ty = t >> 6;   // ty 0..3
    const float* fb = feat + (size_t)b * NC * NPTS;

    {   // position of each point (sorted destination)
        const int n = n0 + t;
        if (n < NPTS) {
            const unsigned pk = idxrank[(size_t)b * NPTS + n];
            posbuf[t] = offsets[b * NVOX + (int)(pk >> 16)] + (int)(pk & 0xFFFFu);
        }
    }

    // load 256 points x 64 ch as float4 (NPTS % 4 == 0), convert to bf16
    const int n4 = n0 + 4 * tx;
    if (n4 < NPTS) {
#pragma unroll
        for (int c = ty; c < 64; c += 4) {
            const float4 v = *(const float4*)&fb[(size_t)c * NPTS + n4];
            unsigned short* row = &tile[c][4 * tx];
            row[0] = f2bf(v.x); row[1] = f2bf(v.y);
            row[2] = f2bf(v.z); row[3] = f2bf(v.w);
        }
    }
    __syncthreads();

    unsigned short* fSb = fS + (size_t)b * NPTS * 64;
    const int nmax = min(256, NPTS - n0);
    for (int j = t; j < nmax * 16; j += 256) {
        const int r = j >> 4, q = j & 15;     // point r, chunk q (4 channels)
        const int pos = posbuf[r];
        ushort4 v;
        v.x = tile[4 * q][r];
        v.y = tile[4 * q + 1][r];
        v.z = tile[4 * q + 2][r];
        v.w = tile[4 * q + 3][r];
        nt_store_us4(v, &fSb[((size_t)pos * 16 + q) * 4]);
    }
}

// ---------------------------------------------------------------------------
// Kernel 6 (single-pass): gather all 64 channels, NO atomics.
//   - wave = 8 point-slots x 8 channel-chunks, 16B uint4 loads
//   - QUAD-issue loads (4 in flight) + dual/single tail
//   - z-interleaved voxel->wave map (vsel = k*8+wid)
//   - empty voxels: 64-lane zero-fill early-out
//   - transposed LDS tile [C][65]; nontemporal coalesced out writes
// ---------------------------------------------------------------------------
__global__ __launch_bounds__(512) void gather64_kernel(
        const unsigned short* __restrict__ fS,
        const int* __restrict__ offsets, const int* __restrict__ counts,
        float* __restrict__ out) {
    __shared__ float tile[NC][65];   // [channel][voxel-in-block]
    const int b    = blockIdx.y;
    const int v0   = blockIdx.x * 64;
    const int t    = threadIdx.x;
    const int wid  = t >> 6;          // 0..7
    const int lane = t & 63;
    const int cq   = lane & 7;        // 16B channel chunk (8 channels)
    const int ps   = lane >> 3;       // point slot 0..7

    const int svL  = offsets[b * NVOX + v0 + lane];
    const int cntL = counts[b * NVOX + v0 + lane];
    const uint4* fS4 = (const uint4*)fS + (size_t)b * NPTS * 8 + cq;

#define ACC8(A0,A1,A2,A3,A4,A5,A6,A7,d)                      \
    A0 += __uint_as_float((d).x << 16);                      \
    A1 += __uint_as_float((d).x & 0xffff0000u);              \
    A2 += __uint_as_float((d).y << 16);                      \
    A3 += __uint_as_float((d).y & 0xffff0000u);              \
    A4 += __uint_as_float((d).z << 16);                      \
    A5 += __uint_as_float((d).z & 0xffff0000u);              \
    A6 += __uint_as_float((d).w << 16);                      \
    A7 += __uint_as_float((d).w & 0xffff0000u);

#pragma unroll 1
    for (int k = 0; k < 8; ++k) {
        const int vsel = k * 8 + wid;   // z-interleave: balance dense z-bands
        const int s    = __shfl(svL, vsel, 64);
        const int cnt  = __shfl(cntL, vsel, 64);

        if (cnt == 0) {                 // wave-uniform: ~82% of voxels
            tile[lane][vsel] = 0.f;     // lane = channel, 2-way alias = free
            continue;
        }

        float a0 = 0.f, a1 = 0.f, a2 = 0.f, a3 = 0.f,
              a4 = 0.f, a5 = 0.f, a6 = 0.f, a7 = 0.f;
        float c0 = 0.f, c1 = 0.f, c2 = 0.f, c3 = 0.f,
              c4 = 0.f, c5 = 0.f, c6 = 0.f, c7 = 0.f;
        const int e = s + cnt;
        int p = s + ps;
        // quad-issue: 4 independent 16B loads in flight per stage
        for (; p + 24 < e; p += 32) {
            const uint4 d0 = fS4[(size_t)(p     ) * 8];
            const uint4 d1 = fS4[(size_t)(p +  8) * 8];
            const uint4 d2 = fS4[(size_t)(p + 16) * 8];
            const uint4 d3 = fS4[(size_t)(p + 24) * 8];
            ACC8(a0, a1, a2, a3, a4, a5, a6, a7, d0)
            ACC8(c0, c1, c2, c3, c4, c5, c6, c7, d1)
            ACC8(a0, a1, a2, a3, a4, a5, a6, a7, d2)
            ACC8(c0, c1, c2, c3, c4, c5, c6, c7, d3)
        }
        if (p + 8 < e) {                // 2-3 loads remain: dual
            const uint4 d0 = fS4[(size_t)p * 8];
            const uint4 d1 = fS4[(size_t)(p + 8) * 8];
            ACC8(a0, a1, a2, a3, a4, a5, a6, a7, d0)
            ACC8(c0, c1, c2, c3, c4, c5, c6, c7, d1)
            p += 16;
        }
        if (p < e) {                    // last load
            const uint4 d0 = fS4[(size_t)p * 8];
            ACC8(a0, a1, a2, a3, a4, a5, a6, a7, d0)
        }
        a0 += c0; a1 += c1; a2 += c2; a3 += c3;
        a4 += c4; a5 += c5; a6 += c6; a7 += c7;

        // reduce across the 8 point slots (ps bits = lane bits 3..5)
#pragma unroll
        for (int m = 8; m < 64; m <<= 1) {
            a0 += __shfl_xor(a0, m, 64);
            a1 += __shfl_xor(a1, m, 64);
            a2 += __shfl_xor(a2, m, 64);
            a3 += __shfl_xor(a3, m, 64);
            a4 += __shfl_xor(a4, m, 64);
            a5 += __shfl_xor(a5, m, 64);
            a6 += __shfl_xor(a6, m, 64);
            a7 += __shfl_xor(a7, m, 64);
        }

        const float inv = 1.0f / fmaxf((float)cnt, 1.f);
        if (ps == 0) {
            tile[8 * cq + 0][vsel] = a0 * inv; tile[8 * cq + 1][vsel] = a1 * inv;
            tile[8 * cq + 2][vsel] = a2 * inv; tile[8 * cq + 3][vsel] = a3 * inv;
        } else if (ps == 1) {
            tile[8 * cq + 4][vsel] = a4 * inv; tile[8 * cq + 5][vsel] = a5 * inv;
            tile[8 * cq + 6][vsel] = a6 * inv; tile[8 * cq + 7][vsel] = a7 * inv;
        }
    }
#undef ACC8
    __syncthreads();

#pragma unroll
    for (int i = t; i < 64 * NC; i += 512) {
        const int v = i & 63, c = i >> 6;
        __builtin_nontemporal_store(
            tile[c][v], &out[(size_t)b * NC * NVOX + (size_t)c * NVOX + v0 + v]);
    }
}

// ---------------------------------------------------------------------------
// Multi-pass kernels (smaller-workspace fallback, CH in {16,8,4,2})
// ---------------------------------------------------------------------------
template <int CH>
__global__ __launch_bounds__(256) void permute_kernel(
        const float* __restrict__ feat,
        const unsigned int* __restrict__ idxrank,
        const int* __restrict__ offsets,
        unsigned short* __restrict__ fS, int c0) {
    __shared__ float tile[CH][257];
    __shared__ int posbuf[256];
    const int b  = blockIdx.y;
    const int n0 = blockIdx.x * 256;
    const int t  = threadIdx.x;
    const int n  = n0 + t;
    const float* fb = feat + (size_t)b * NC * NPTS + (size_t)c0 * NPTS;
    if (n < NPTS) {
        const unsigned pk = idxrank[(size_t)b * NPTS + n];
        posbuf[t] = offsets[b * NVOX + (int)(pk >> 16)] + (int)(pk & 0xFFFFu);
#pragma unroll
        for (int c = 0; c < CH; ++c)
            tile[c][t] = fb[(size_t)c * NPTS + n];
    }
    __syncthreads();
    ushort2* fS2 = (ushort2*)fS + (size_t)b * NPTS * (CH / 2);
    const int nmax = min(256, NPTS - n0);
    for (int j = t; j < nmax * (CH / 2); j += 256) {
        const int r  = j / (CH / 2);
        const int cp = j - r * (CH / 2);
        const int pos = posbuf[r];
        ushort2 v;
        v.x = f2bf(tile[2 * cp][r]);
        v.y = f2bf(tile[2 * cp + 1][r]);
        fS2[(size_t)pos * (CH / 2) + cp] = v;
    }
}

template <int CH>
__global__ __launch_bounds__(512) void gather_kernel(
        const unsigned short* __restrict__ fS,
        const int* __restrict__ offsets, const int* __restrict__ counts,
        float* __restrict__ out, int c0) {
    constexpr int HP  = CH / 2;
    constexpr int PPW = 64 / HP;
    __shared__ float tile[64][CH + 2];
    const int b    = blockIdx.y;
    const int v0   = blockIdx.x * 64;
    const int t    = threadIdx.x;
    const int wid  = t >> 6;
    const int lane = t & 63;
    const int pr   = lane % HP;
    const int ps   = lane / HP;

    const int svL  = offsets[b * NVOX + v0 + lane];
    const int cntL = counts[b * NVOX + v0 + lane];
    const ushort2* fS2 = (const ushort2*)fS + (size_t)b * NPTS * HP;

#pragma unroll
    for (int k = 0; k < 8; ++k) {
        const int vsel = wid * 8 + k;
        const int s    = __shfl(svL, vsel, 64);
        const int cnt  = __shfl(cntL, vsel, 64);
        float ax = 0.f, ay = 0.f;
        const int e = s + cnt;
        for (int p = s + ps; p < e; p += PPW) {
            const ushort2 d = fS2[(size_t)p * HP + pr];
            ax += bf2f(d.x);
            ay += bf2f(d.y);
        }
        for (int m = HP; m < 64; m <<= 1) {
            ax += __shfl_xor(ax, m, 64);
            ay += __shfl_xor(ay, m, 64);
        }
        if (ps == 0) {
            const float cf = fmaxf((float)cnt, 1.f);
            *(float2*)&tile[vsel][2 * pr] = make_float2(ax / cf, ay / cf);
        }
    }
    __syncthreads();

#pragma unroll
    for (int i = t; i < 64 * CH; i += 512) {
        const int v = i & 63, c = i >> 6;
        out[(size_t)b * NC * NVOX + (size_t)(c0 + c) * NVOX + v0 + v] = tile[v][c];
    }
}

// ---------------------------------------------------------------------------
// Tiny-workspace fallback: direct global-atomic scatter + divide
// ---------------------------------------------------------------------------
__global__ void scatter_fb(const float* __restrict__ feat,
                           const unsigned int* __restrict__ idxrank,
                           float* __restrict__ out) {
    const int n = blockIdx.x * 256 + threadIdx.x;
    const int b = blockIdx.y;
    if (n >= NPTS) return;
    const int idx = (int)(idxrank[(size_t)b * NPTS + n] >> 16);
    const float* fb = feat + (size_t)b * NC * NPTS + n;
    float* ob = out + (size_t)b * NC * NVOX + idx;
#pragma unroll 4
    for (int c = 0; c < NC; ++c)
        atomicAdd(ob + (size_t)c * NVOX, fb[(size_t)c * NPTS]);
}

__global__ void div_fb(float* __restrict__ out, const int* __restrict__ counts) {
    const int t = blockIdx.x * blockDim.x + threadIdx.x;
    const int b = t >> 15;
    const int v = t & (NVOX - 1);
    const float cnt = fmaxf((float)counts[t], 1.f);
    float* ob = out + (size_t)b * NC * NVOX + v;
#pragma unroll 8
    for (int c = 0; c < NC; ++c)
        ob[(size_t)c * NVOX] /= cnt;
}

// ---------------------------------------------------------------------------
template <int CH>
static void run_passes(const float* feat, unsigned int* idxrank, int* offsets,
                       int* counts, unsigned short* fS, float* out,
                       hipStream_t stream) {
    for (int c0 = 0; c0 < NC; c0 += CH) {
        permute_kernel<CH><<<dim3(NTILE, NB), 256, 0, stream>>>(
            feat, idxrank, offsets, fS, c0);
        gather_kernel<CH><<<dim3(NVOX / 64, NB), 512, 0, stream>>>(
            fS, offsets, counts, out, c0);
    }
}

extern "C" void kernel_launch(void* const* d_in, const int* in_sizes, int n_in,
                              void* d_out, int out_size, void* d_ws, size_t ws_size,
                              hipStream_t stream) {
    const float* feat   = (const float*)d_in[0];  // [8,64,100000]
    const float* coords = (const float*)d_in[1];  // [8,3,100000]

    float* out      = (float*)d_out;                 // [8,64,32,32,32]
    float* norm_out = out + (size_t)NB * NC * NVOX;  // [8,3,100000]

    float*          ws_sum  = (float*)d_ws + SUM_OFF;
    unsigned int*   ws_rad  = (unsigned int*)d_ws + RAD_OFF;
    int*            counts  = (int*)d_ws + CNT_OFF;
    int*            offsets = (int*)d_ws + OFF_OFF;
    unsigned int*   idxrank = (unsigned int*)d_ws + IR_OFF;
    unsigned short* fS      = (unsigned short*)((int*)d_ws + FS_OFF);

    // largest channel chunk that fits the workspace (bf16 featS)
    int CH = 0;
    for (int ch = 64; ch >= 2; ch >>= 1) {
        const size_t need = (size_t)FS_OFF * 4 + (size_t)NB * NPTS * ch * 2;
        if (ws_size >= need) { CH = ch; break; }
    }
    if (CH == 32) CH = 16;   // no 32-wide template; use 16

    hipMemsetAsync(d_ws, 0, ((size_t)CNT_OFF + (size_t)NB * NVOX) * 4, stream);

    sum_kernel<<<dim3(32, NB), 256, 0, stream>>>(coords, ws_sum);
    rad_kernel<<<dim3(32, NB), 256, 0, stream>>>(coords, ws_sum, ws_rad);
    index_kernel<<<dim3(NTILE4, NB), 256, 0, stream>>>(
        coords, ws_sum, ws_rad, norm_out, idxrank, counts);

    if (CH == 0) {
        hipMemsetAsync(d_out, 0, (size_t)NB * NC * NVOX * 4, stream);
        scatter_fb<<<dim3(NTILE, NB), 256, 0, stream>>>(feat, idxrank, out);
        div_fb<<<dim3(NB * NVOX / 256), 256, 0, stream>>>(out, counts);
        return;
    }

    scan_kernel<<<dim3(NB), 1024, 0, stream>>>(counts, offsets);

    if (CH == 64) {
        permute64_kernel<<<dim3(NTILE, NB), 256, 0, stream>>>(
            feat, idxrank, offsets, fS);
        gather64_kernel<<<dim3(NVOX / 64, NB), 512, 0, stream>>>(
            fS, offsets, counts, out);
    } else {
        switch (CH) {
            case 16: run_passes<16>(feat, idxrank, offsets, counts, fS, out, stream); break;
            case 8:  run_passes<8>(feat, idxrank, offsets, counts, fS, out, stream); break;
            case 4:  run_passes<4>(feat, idxrank, offsets, counts, fS, out, stream); break;
            default: run_passes<2>(feat, idxrank, offsets, counts, fS, out, stream); break;
        }
    }
}

// Round 7
// 468.071 us; speedup vs baseline: 1.2507x; 1.0200x over previous
//
#include <hip/hip_runtime.h>

#define RES   32
#define NVOX  (RES * RES * RES)   // 32768
#define NB    8
#define NC    64
#define NPTS  100000
#define NTILE   ((NPTS + 255) / 256)      // 391
#define NTILE4  ((NPTS / 4 + 255) / 256)  // 98  (4 points per thread)

// workspace layout in 4-byte words
#define SUM_OFF  0                          // 24 floats
#define RAD_OFF  32                         // 8 uints
#define CNT_OFF  64                         // NB*NVOX ints        (1 MB)
#define OFF_OFF  (CNT_OFF + NB * NVOX)      // NB*NVOX ints        (1 MB)
#define IR_OFF   (OFF_OFF + NB * NVOX)      // NB*NPTS uints       (3.2 MB)  (idx<<16)|rank
#define FS_OFF   (IR_OFF  + NB * NPTS)      // featS bf16: NB*NPTS*CH*2 bytes

// native Clang vectors for nontemporal builtins (HIP_vector_type is a struct
// and __builtin_nontemporal_store rejects it)
typedef float f32x4 __attribute__((ext_vector_type(4)));

__device__ __forceinline__ void nt_store_f4(const float4& v, float* p) {
    f32x4 w = {v.x, v.y, v.z, v.w};
    __builtin_nontemporal_store(w, (f32x4*)p);
}

__device__ __forceinline__ unsigned short f2bf(float x) {
    unsigned u = __float_as_uint(x);
    return (unsigned short)((u + 0x7FFFu + ((u >> 16) & 1u)) >> 16);  // RNE
}
__device__ __forceinline__ float bf2f(unsigned short h) {
    return __uint_as_float((unsigned)h << 16);
}

// ---------------------------------------------------------------------------
// Kernel 1: per-batch sum of coords -> ws_sum[b*3+k]   (float4, 4 pts/iter)
// ---------------------------------------------------------------------------
__global__ void sum_kernel(const float* __restrict__ coords,
                           float* __restrict__ ws_sum) {
    const int b = blockIdx.y;
    const float* cb = coords + (size_t)b * 3 * NPTS;
    float s0 = 0.f, s1 = 0.f, s2 = 0.f;
    for (int i = blockIdx.x * blockDim.x + threadIdx.x; i < NPTS / 4;
         i += blockDim.x * gridDim.x) {
        const float4 a = *(const float4*)&cb[4 * i];
        const float4 c = *(const float4*)&cb[NPTS + 4 * i];
        const float4 d = *(const float4*)&cb[2 * NPTS + 4 * i];
        s0 += (a.x + a.y) + (a.z + a.w);
        s1 += (c.x + c.y) + (c.z + c.w);
        s2 += (d.x + d.y) + (d.z + d.w);
    }
    for (int off = 32; off > 0; off >>= 1) {
        s0 += __shfl_down(s0, off, 64);
        s1 += __shfl_down(s1, off, 64);
        s2 += __shfl_down(s2, off, 64);
    }
    if ((threadIdx.x & 63) == 0) {
        atomicAdd(&ws_sum[b * 3 + 0], s0);
        atomicAdd(&ws_sum[b * 3 + 1], s1);
        atomicAdd(&ws_sum[b * 3 + 2], s2);
    }
}

// ---------------------------------------------------------------------------
// Kernel 2: per-batch max squared radius -> ws_rad[b]  (float4, 4 pts/iter)
// ---------------------------------------------------------------------------
__global__ void rad_kernel(const float* __restrict__ coords,
                           const float* __restrict__ ws_sum,
                           unsigned int* __restrict__ ws_rad) {
#pragma clang fp contract(off)
    const int b = blockIdx.y;
    const float* cb = coords + (size_t)b * 3 * NPTS;
    const float m0 = ws_sum[b * 3 + 0] / (float)NPTS;
    const float m1 = ws_sum[b * 3 + 1] / (float)NPTS;
    const float m2 = ws_sum[b * 3 + 2] / (float)NPTS;
    float mx = 0.f;
    for (int i = blockIdx.x * blockDim.x + threadIdx.x; i < NPTS / 4;
         i += blockDim.x * gridDim.x) {
        const float4 a = *(const float4*)&cb[4 * i];
        const float4 c = *(const float4*)&cb[NPTS + 4 * i];
        const float4 d = *(const float4*)&cb[2 * NPTS + 4 * i];
        const float dx0 = a.x - m0, dy0 = c.x - m1, dz0 = d.x - m2;
        const float dx1 = a.y - m0, dy1 = c.y - m1, dz1 = d.y - m2;
        const float dx2 = a.z - m0, dy2 = c.z - m1, dz2 = d.z - m2;
        const float dx3 = a.w - m0, dy3 = c.w - m1, dz3 = d.w - m2;
        mx = fmaxf(mx, dx0 * dx0 + dy0 * dy0 + dz0 * dz0);
        mx = fmaxf(mx, dx1 * dx1 + dy1 * dy1 + dz1 * dz1);
        mx = fmaxf(mx, dx2 * dx2 + dy2 * dy2 + dz2 * dz2);
        mx = fmaxf(mx, dx3 * dx3 + dy3 * dy3 + dz3 * dz3);
    }
    for (int off = 32; off > 0; off >>= 1)
        mx = fmaxf(mx, __shfl_down(mx, off, 64));
    if ((threadIdx.x & 63) == 0)
        atomicMax(&ws_rad[b], __float_as_uint(mx));
}

// ---------------------------------------------------------------------------
// Kernel 3: per point: norm coords (output 1), voxel idx, histogram + rank.
//   4 points per thread: float4 loads; nt stores ONLY for write-once norm_out;
//   idxrank is re-read by permute64 -> cached store.
// ---------------------------------------------------------------------------
__global__ void index_kernel(const float* __restrict__ coords,
                             const float* __restrict__ ws_sum,
                             const unsigned int* __restrict__ ws_rad,
                             float* __restrict__ norm_out,
                             unsigned int* __restrict__ idxrank,
                             int* __restrict__ counts) {
#pragma clang fp contract(off)
    const int i = blockIdx.x * blockDim.x + threadIdx.x;
    const int b = blockIdx.y;
    const int n4 = i * 4;
    if (n4 >= NPTS) return;   // NPTS % 4 == 0 -> full quads only

    const float m0 = ws_sum[b * 3 + 0] / (float)NPTS;
    const float m1 = ws_sum[b * 3 + 1] / (float)NPTS;
    const float m2 = ws_sum[b * 3 + 2] / (float)NPTS;
    const float r  = sqrtf(__uint_as_float(ws_rad[b]));
    const float d  = r * 2.0f;   // EPS == 0

    const float* cb = coords + (size_t)b * 3 * NPTS;
    const float4 xs = *(const float4*)&cb[n4];
    const float4 ys = *(const float4*)&cb[NPTS + n4];
    const float4 zs = *(const float4*)&cb[2 * NPTS + n4];

    float4 nx4, ny4, nz4;
    int idx0, idx1, idx2, idx3;
#define DOPT(J, OUTX, OUTY, OUTZ, IDX)                                         \
    {                                                                          \
        const float x = xs.J - m0, y = ys.J - m1, z = zs.J - m2;               \
        const float nx = fminf(fmaxf((x / d + 0.5f) * (float)RES, 0.0f),       \
                               (float)(RES - 1));                              \
        const float ny = fminf(fmaxf((y / d + 0.5f) * (float)RES, 0.0f),       \
                               (float)(RES - 1));                              \
        const float nz = fminf(fmaxf((z / d + 0.5f) * (float)RES, 0.0f),       \
                               (float)(RES - 1));                              \
        OUTX = nx; OUTY = ny; OUTZ = nz;                                       \
        IDX = ((int)rintf(nx) * RES + (int)rintf(ny)) * RES + (int)rintf(nz);  \
    }
    DOPT(x, nx4.x, ny4.x, nz4.x, idx0)
    DOPT(y, nx4.y, ny4.y, nz4.y, idx1)
    DOPT(z, nx4.z, ny4.z, nz4.z, idx2)
    DOPT(w, nx4.w, ny4.w, nz4.w, idx3)
#undef DOPT

    float* nb_ = norm_out + (size_t)b * 3 * NPTS;   // write-once: nt ok
    nt_store_f4(nx4, &nb_[n4]);
    nt_store_f4(ny4, &nb_[NPTS + n4]);
    nt_store_f4(nz4, &nb_[2 * NPTS + n4]);

    int* cnt_b = counts + (size_t)b * NVOX;
    uint4 ir;
    ir.x = ((unsigned)idx0 << 16) | (unsigned)(atomicAdd(&cnt_b[idx0], 1) & 0xFFFF);
    ir.y = ((unsigned)idx1 << 16) | (unsigned)(atomicAdd(&cnt_b[idx1], 1) & 0xFFFF);
    ir.z = ((unsigned)idx2 << 16) | (unsigned)(atomicAdd(&cnt_b[idx2], 1) & 0xFFFF);
    ir.w = ((unsigned)idx3 << 16) | (unsigned)(atomicAdd(&cnt_b[idx3], 1) & 0xFFFF);
    *(uint4*)&idxrank[(size_t)b * NPTS + n4] = ir;   // re-read: cached store
}

// ---------------------------------------------------------------------------
// Kernel 4: per-batch exclusive scan of 32768 counts -> offsets (int4 I/O)
// ---------------------------------------------------------------------------
__global__ __launch_bounds__(1024) void scan_kernel(const int* __restrict__ counts,
                                                    int* __restrict__ offsets) {
    const int b = blockIdx.x;
    const int t = threadIdx.x;            // each owns 32 values
    const int base = b * NVOX + t * 32;
    const int4* cp4 = (const int4*)(counts + base);
    int4* op4 = (int4*)(offsets + base);

    const int4 q0 = cp4[0], q1 = cp4[1], q2 = cp4[2], q3 = cp4[3];
    const int4 q4 = cp4[4], q5 = cp4[5], q6 = cp4[6], q7 = cp4[7];
#define QS(Q) ((Q.x + Q.y) + (Q.z + Q.w))
    const int sum = ((QS(q0) + QS(q1)) + (QS(q2) + QS(q3))) +
                    ((QS(q4) + QS(q5)) + (QS(q6) + QS(q7)));
#undef QS

    const int lane = t & 63, wid = t >> 6;  // 16 waves
    int x = sum;
    for (int off = 1; off < 64; off <<= 1) {
        int y = __shfl_up(x, off, 64);
        if (lane >= off) x += y;
    }
    __shared__ int wsum[16];
    if (lane == 63) wsum[wid] = x;
    __syncthreads();
    if (t == 0) {
        int run = 0;
        for (int w = 0; w < 16; ++w) { int tmp = wsum[w]; wsum[w] = run; run += tmp; }
    }
    __syncthreads();
    int run = x - sum + wsum[wid];
#define EMIT(Q, S)                                                   \
    {                                                                \
        int4 o;                                                      \
        o.x = run; run += Q.x; o.y = run; run += Q.y;                \
        o.z = run; run += Q.z; o.w = run; run += Q.w;                \
        op4[S] = o;                                                  \
    }
    EMIT(q0, 0) EMIT(q1, 1) EMIT(q2, 2) EMIT(q3, 3)
    EMIT(q4, 4) EMIT(q5, 5) EMIT(q6, 6) EMIT(q7, 7)
#undef EMIT
}

// ---------------------------------------------------------------------------
// Kernel 5 (single-pass): permute ALL 64 channels into sorted order (bf16).
//   256-point blocks: float4 global loads (16B/lane), bf16 LDS tile, phase 2
//   pack-only. fS is RE-READ by gather64 -> plain (cached) stores so the
//   102 MB tile stays LLC-resident.
// ---------------------------------------------------------------------------
__global__ __launch_bounds__(256) void permute64_kernel(
        const float* __restrict__ feat,
        const unsigned int* __restrict__ idxrank,
        const int* __restrict__ offsets,
        unsigned short* __restrict__ fS) {
    __shared__ unsigned short tile[64][260];   // bf16; stride 260 -> 8B-aligned rows
    __shared__ int posbuf[256];
    const int b  = blockIdx.y;
    const int n0 = blockIdx.x * 256;
    const int t  = threadIdx.x;
    const int tx = t & 63, ty = t >> 6;   // ty 0..3
    const float* fb = feat + (size_t)b * NC * NPTS;

    {   // position of each point (sorted destination)
        const int n = n0 + t;
        if (n < NPTS) {
            const unsigned pk = idxrank[(size_t)b * NPTS + n];
            posbuf[t] = offsets[b * NVOX + (int)(pk >> 16)] + (int)(pk & 0xFFFFu);
        }
    }

    // load 256 points x 64 ch as float4 (NPTS % 4 == 0), convert to bf16
    const int n4 = n0 + 4 * tx;
    if (n4 < NPTS) {
#pragma unroll
        for (int c = ty; c < 64; c += 4) {
            const float4 v = *(const float4*)&fb[(size_t)c * NPTS + n4];
            unsigned short* row = &tile[c][4 * tx];
            row[0] = f2bf(v.x); row[1] = f2bf(v.y);
            row[2] = f2bf(v.z); row[3] = f2bf(v.w);
        }
    }
    __syncthreads();

    ushort4* fS4 = (ushort4*)fS + (size_t)b * NPTS * 16;
    const int nmax = min(256, NPTS - n0);
    for (int j = t; j < nmax * 16; j += 256) {
        const int r = j >> 4, q = j & 15;     // point r, chunk q (4 channels)
        const int pos = posbuf[r];
        ushort4 v;
        v.x = tile[4 * q][r];
        v.y = tile[4 * q + 1][r];
        v.z = tile[4 * q + 2][r];
        v.w = tile[4 * q + 3][r];
        fS4[(size_t)pos * 16 + q] = v;
    }
}

// ---------------------------------------------------------------------------
// Kernel 6 (single-pass): gather all 64 channels, NO atomics.
//   - wave = 8 point-slots x 8 channel-chunks, 16B uint4 loads
//   - QUAD-issue loads (4 in flight) + dual/single tail
//   - z-interleaved voxel->wave map (vsel = k*8+wid)
//   - empty voxels: 64-lane zero-fill early-out
//   - transposed LDS tile [C][65]; nontemporal coalesced out writes
// ---------------------------------------------------------------------------
__global__ __launch_bounds__(512) void gather64_kernel(
        const unsigned short* __restrict__ fS,
        const int* __restrict__ offsets, const int* __restrict__ counts,
        float* __restrict__ out) {
    __shared__ float tile[NC][65];   // [channel][voxel-in-block]
    const int b    = blockIdx.y;
    const int v0   = blockIdx.x * 64;
    const int t    = threadIdx.x;
    const int wid  = t >> 6;          // 0..7
    const int lane = t & 63;
    const int cq   = lane & 7;        // 16B channel chunk (8 channels)
    const int ps   = lane >> 3;       // point slot 0..7

    const int svL  = offsets[b * NVOX + v0 + lane];
    const int cntL = counts[b * NVOX + v0 + lane];
    const uint4* fS4 = (const uint4*)fS + (size_t)b * NPTS * 8 + cq;

#define ACC8(A0,A1,A2,A3,A4,A5,A6,A7,d)                      \
    A0 += __uint_as_float((d).x << 16);                      \
    A1 += __uint_as_float((d).x & 0xffff0000u);              \
    A2 += __uint_as_float((d).y << 16);                      \
    A3 += __uint_as_float((d).y & 0xffff0000u);              \
    A4 += __uint_as_float((d).z << 16);                      \
    A5 += __uint_as_float((d).z & 0xffff0000u);              \
    A6 += __uint_as_float((d).w << 16);                      \
    A7 += __uint_as_float((d).w & 0xffff0000u);

#pragma unroll 1
    for (int k = 0; k < 8; ++k) {
        const int vsel = k * 8 + wid;   // z-interleave: balance dense z-bands
        const int s    = __shfl(svL, vsel, 64);
        const int cnt  = __shfl(cntL, vsel, 64);

        if (cnt == 0) {                 // wave-uniform: ~82% of voxels
            tile[lane][vsel] = 0.f;     // lane = channel, 2-way alias = free
            continue;
        }

        float a0 = 0.f, a1 = 0.f, a2 = 0.f, a3 = 0.f,
              a4 = 0.f, a5 = 0.f, a6 = 0.f, a7 = 0.f;
        float c0 = 0.f, c1 = 0.f, c2 = 0.f, c3 = 0.f,
              c4 = 0.f, c5 = 0.f, c6 = 0.f, c7 = 0.f;
        const int e = s + cnt;
        int p = s + ps;
        // quad-issue: 4 independent 16B loads in flight per stage
        for (; p + 24 < e; p += 32) {
            const uint4 d0 = fS4[(size_t)(p     ) * 8];
            const uint4 d1 = fS4[(size_t)(p +  8) * 8];
            const uint4 d2 = fS4[(size_t)(p + 16) * 8];
            const uint4 d3 = fS4[(size_t)(p + 24) * 8];
            ACC8(a0, a1, a2, a3, a4, a5, a6, a7, d0)
            ACC8(c0, c1, c2, c3, c4, c5, c6, c7, d1)
            ACC8(a0, a1, a2, a3, a4, a5, a6, a7, d2)
            ACC8(c0, c1, c2, c3, c4, c5, c6, c7, d3)
        }
        if (p + 8 < e) {                // 2-3 loads remain: dual
            const uint4 d0 = fS4[(size_t)p * 8];
            const uint4 d1 = fS4[(size_t)(p + 8) * 8];
            ACC8(a0, a1, a2, a3, a4, a5, a6, a7, d0)
            ACC8(c0, c1, c2, c3, c4, c5, c6, c7, d1)
            p += 16;
        }
        if (p < e) {                    // last load
            const uint4 d0 = fS4[(size_t)p * 8];
            ACC8(a0, a1, a2, a3, a4, a5, a6, a7, d0)
        }
        a0 += c0; a1 += c1; a2 += c2; a3 += c3;
        a4 += c4; a5 += c5; a6 += c6; a7 += c7;

        // reduce across the 8 point slots (ps bits = lane bits 3..5)
#pragma unroll
        for (int m = 8; m < 64; m <<= 1) {
            a0 += __shfl_xor(a0, m, 64);
            a1 += __shfl_xor(a1, m, 64);
            a2 += __shfl_xor(a2, m, 64);
            a3 += __shfl_xor(a3, m, 64);
            a4 += __shfl_xor(a4, m, 64);
            a5 += __shfl_xor(a5, m, 64);
            a6 += __shfl_xor(a6, m, 64);
            a7 += __shfl_xor(a7, m, 64);
        }

        const float inv = 1.0f / fmaxf((float)cnt, 1.f);
        if (ps == 0) {
            tile[8 * cq + 0][vsel] = a0 * inv; tile[8 * cq + 1][vsel] = a1 * inv;
            tile[8 * cq + 2][vsel] = a2 * inv; tile[8 * cq + 3][vsel] = a3 * inv;
        } else if (ps == 1) {
            tile[8 * cq + 4][vsel] = a4 * inv; tile[8 * cq + 5][vsel] = a5 * inv;
            tile[8 * cq + 6][vsel] = a6 * inv; tile[8 * cq + 7][vsel] = a7 * inv;
        }
    }
#undef ACC8
    __syncthreads();

#pragma unroll
    for (int i = t; i < 64 * NC; i += 512) {
        const int v = i & 63, c = i >> 6;
        __builtin_nontemporal_store(
            tile[c][v], &out[(size_t)b * NC * NVOX + (size_t)c * NVOX + v0 + v]);
    }
}

// ---------------------------------------------------------------------------
// Multi-pass kernels (smaller-workspace fallback, CH in {16,8,4,2})
// ---------------------------------------------------------------------------
template <int CH>
__global__ __launch_bounds__(256) void permute_kernel(
        const float* __restrict__ feat,
        const unsigned int* __restrict__ idxrank,
        const int* __restrict__ offsets,
        unsigned short* __restrict__ fS, int c0) {
    __shared__ float tile[CH][257];
    __shared__ int posbuf[256];
    const int b  = blockIdx.y;
    const int n0 = blockIdx.x * 256;
    const int t  = threadIdx.x;
    const int n  = n0 + t;
    const float* fb = feat + (size_t)b * NC * NPTS + (size_t)c0 * NPTS;
    if (n < NPTS) {
        const unsigned pk = idxrank[(size_t)b * NPTS + n];
        posbuf[t] = offsets[b * NVOX + (int)(pk >> 16)] + (int)(pk & 0xFFFFu);
#pragma unroll
        for (int c = 0; c < CH; ++c)
            tile[c][t] = fb[(size_t)c * NPTS + n];
    }
    __syncthreads();
    ushort2* fS2 = (ushort2*)fS + (size_t)b * NPTS * (CH / 2);
    const int nmax = min(256, NPTS - n0);
    for (int j = t; j < nmax * (CH / 2); j += 256) {
        const int r  = j / (CH / 2);
        const int cp = j - r * (CH / 2);
        const int pos = posbuf[r];
        ushort2 v;
        v.x = f2bf(tile[2 * cp][r]);
        v.y = f2bf(tile[2 * cp + 1][r]);
        fS2[(size_t)pos * (CH / 2) + cp] = v;
    }
}

template <int CH>
__global__ __launch_bounds__(512) void gather_kernel(
        const unsigned short* __restrict__ fS,
        const int* __restrict__ offsets, const int* __restrict__ counts,
        float* __restrict__ out, int c0) {
    constexpr int HP  = CH / 2;
    constexpr int PPW = 64 / HP;
    __shared__ float tile[64][CH + 2];
    const int b    = blockIdx.y;
    const int v0   = blockIdx.x * 64;
    const int t    = threadIdx.x;
    const int wid  = t >> 6;
    const int lane = t & 63;
    const int pr   = lane % HP;
    const int ps   = lane / HP;

    const int svL  = offsets[b * NVOX + v0 + lane];
    const int cntL = counts[b * NVOX + v0 + lane];
    const ushort2* fS2 = (const ushort2*)fS + (size_t)b * NPTS * HP;

#pragma unroll
    for (int k = 0; k < 8; ++k) {
        const int vsel = wid * 8 + k;
        const int s    = __shfl(svL, vsel, 64);
        const int cnt  = __shfl(cntL, vsel, 64);
        float ax = 0.f, ay = 0.f;
        const int e = s + cnt;
        for (int p = s + ps; p < e; p += PPW) {
            const ushort2 d = fS2[(size_t)p * HP + pr];
            ax += bf2f(d.x);
            ay += bf2f(d.y);
        }
        for (int m = HP; m < 64; m <<= 1) {
            ax += __shfl_xor(ax, m, 64);
            ay += __shfl_xor(ay, m, 64);
        }
        if (ps == 0) {
            const float cf = fmaxf((float)cnt, 1.f);
            *(float2*)&tile[vsel][2 * pr] = make_float2(ax / cf, ay / cf);
        }
    }
    __syncthreads();

#pragma unroll
    for (int i = t; i < 64 * CH; i += 512) {
        const int v = i & 63, c = i >> 6;
        out[(size_t)b * NC * NVOX + (size_t)(c0 + c) * NVOX + v0 + v] = tile[v][c];
    }
}

// ---------------------------------------------------------------------------
// Tiny-workspace fallback: direct global-atomic scatter + divide
// ---------------------------------------------------------------------------
__global__ void scatter_fb(const float* __restrict__ feat,
                           const unsigned int* __restrict__ idxrank,
                           float* __restrict__ out) {
    const int n = blockIdx.x * 256 + threadIdx.x;
    const int b = blockIdx.y;
    if (n >= NPTS) return;
    const int idx = (int)(idxrank[(size_t)b * NPTS + n] >> 16);
    const float* fb = feat + (size_t)b * NC * NPTS + n;
    float* ob = out + (size_t)b * NC * NVOX + idx;
#pragma unroll 4
    for (int c = 0; c < NC; ++c)
        atomicAdd(ob + (size_t)c * NVOX, fb[(size_t)c * NPTS]);
}

__global__ void div_fb(float* __restrict__ out, const int* __restrict__ counts) {
    const int t = blockIdx.x * blockDim.x + threadIdx.x;
    const int b = t >> 15;
    const int v = t & (NVOX - 1);
    const float cnt = fmaxf((float)counts[t], 1.f);
    float* ob = out + (size_t)b * NC * NVOX + v;
#pragma unroll 8
    for (int c = 0; c < NC; ++c)
        ob[(size_t)c * NVOX] /= cnt;
}

// ---------------------------------------------------------------------------
template <int CH>
static void run_passes(const float* feat, unsigned int* idxrank, int* offsets,
                       int* counts, unsigned short* fS, float* out,
                       hipStream_t stream) {
    for (int c0 = 0; c0 < NC; c0 += CH) {
        permute_kernel<CH><<<dim3(NTILE, NB), 256, 0, stream>>>(
            feat, idxrank, offsets, fS, c0);
        gather_kernel<CH><<<dim3(NVOX / 64, NB), 512, 0, stream>>>(
            fS, offsets, counts, out, c0);
    }
}

extern "C" void kernel_launch(void* const* d_in, const int* in_sizes, int n_in,
                              void* d_out, int out_size, void* d_ws, size_t ws_size,
                              hipStream_t stream) {
    const float* feat   = (const float*)d_in[0];  // [8,64,100000]
    const float* coords = (const float*)d_in[1];  // [8,3,100000]

    float* out      = (float*)d_out;                 // [8,64,32,32,32]
    float* norm_out = out + (size_t)NB * NC * NVOX;  // [8,3,100000]

    float*          ws_sum  = (float*)d_ws + SUM_OFF;
    unsigned int*   ws_rad  = (unsigned int*)d_ws + RAD_OFF;
    int*            counts  = (int*)d_ws + CNT_OFF;
    int*            offsets = (int*)d_ws + OFF_OFF;
    unsigned int*   idxrank = (unsigned int*)d_ws + IR_OFF;
    unsigned short* fS      = (unsigned short*)((int*)d_ws + FS_OFF);

    // largest channel chunk that fits the workspace (bf16 featS)
    int CH = 0;
    for (int ch = 64; ch >= 2; ch >>= 1) {
        const size_t need = (size_t)FS_OFF * 4 + (size_t)NB * NPTS * ch * 2;
        if (ws_size >= need) { CH = ch; break; }
    }
    if (CH == 32) CH = 16;   // no 32-wide template; use 16

    hipMemsetAsync(d_ws, 0, ((size_t)CNT_OFF + (size_t)NB * NVOX) * 4, stream);

    sum_kernel<<<dim3(32, NB), 256, 0, stream>>>(coords, ws_sum);
    rad_kernel<<<dim3(32, NB), 256, 0, stream>>>(coords, ws_sum, ws_rad);
    index_kernel<<<dim3(NTILE4, NB), 256, 0, stream>>>(
        coords, ws_sum, ws_rad, norm_out, idxrank, counts);

    if (CH == 0) {
        hipMemsetAsync(d_out, 0, (size_t)NB * NC * NVOX * 4, stream);
        scatter_fb<<<dim3(NTILE, NB), 256, 0, stream>>>(feat, idxrank, out);
        div_fb<<<dim3(NB * NVOX / 256), 256, 0, stream>>>(out, counts);
        return;
    }

    scan_kernel<<<dim3(NB), 1024, 0, stream>>>(counts, offsets);

    if (CH == 64) {
        permute64_kernel<<<dim3(NTILE, NB), 256, 0, stream>>>(
            feat, idxrank, offsets, fS);
        gather64_kernel<<<dim3(NVOX / 64, NB), 512, 0, stream>>>(
            fS, offsets, counts, out);
    } else {
        switch (CH) {
            case 16: run_passes<16>(feat, idxrank, offsets, counts, fS, out, stream); break;
            case 8:  run_passes<8>(feat, idxrank, offsets, counts, fS, out, stream); break;
            case 4:  run_passes<4>(feat, idxrank, offsets, counts, fS, out, stream); break;
            default: run_passes<2>(feat, idxrank, offsets, counts, fS, out, stream); break;
        }
    }
}